// Round 2
// baseline (1476.125 us; speedup 1.0000x reference)
//
#include <hip/hip_runtime.h>
#include <hip/hip_bf16.h>
#include <stdint.h>

// ---------------------------------------------------------------------------
// dims
constexpr int BB=16, CIN=32, CO=64, NNODE=1024, TT=24, KTAP=3, DTEM=32, NH=8, HD=8, TO=20;

typedef __attribute__((ext_vector_type(4))) float f32x4;
typedef __attribute__((ext_vector_type(8))) short bf16x8;

__device__ __forceinline__ unsigned short f2bf(float f) {
  union { float f; unsigned u; } v; v.f = f;
  unsigned r = v.u + 0x7FFFu + ((v.u >> 16) & 1u);
  return (unsigned short)(r >> 16);
}
__device__ __forceinline__ float bf2f(unsigned short s) {
  union { unsigned u; float f; } v; v.u = ((unsigned)s) << 16; return v.f;
}

// ---------------------------------------------------------------------------
// K0a: transpose small weights into Wf (fp32) + wg -> bf16
__global__ __launch_bounds__(256) void k_prep_w(
    const float* __restrict__ wtc, const float* __restrict__ wq,
    const float* __restrict__ wk,  const float* __restrict__ wv,
    const float* __restrict__ wo,  const float* __restrict__ wadp,
    const float* __restrict__ w0f, const float* __restrict__ wg0,
    const float* __restrict__ wg1,
    float* __restrict__ Wf, unsigned short* __restrict__ wg0bf,
    unsigned short* __restrict__ wg1bf)
{
  int id = blockIdx.x * 256 + threadIdx.x;
  if (id < 6144) {                       // wtcT[(ci*3+kt)*64+o] = wtc[o][ci][0][kt]
    int o = id & 63, rest = id >> 6, ci = rest / 3, kt = rest % 3;
    Wf[id] = wtc[(o * 32 + ci) * 3 + kt];
  } else if (id < 24576) {               // wqT/wkT/wvT [96][64]
    int j = id - 6144; int m = j / 6144; int jj = j % 6144;
    int o = jj & 63, cc = jj >> 6;
    const float* w = (m == 0) ? wq : (m == 1) ? wk : wv;
    Wf[id] = w[o * 96 + cc];
  } else if (id < 28672) {               // woT [64][64]
    int j = id - 24576; int o = j & 63, cc = j >> 6;
    Wf[id] = wo[o * 64 + cc];
  } else if (id < 36864) {               // wadpT [128][64]
    int j = id - 28672; int o = j & 63, cc = j >> 6;
    Wf[id] = wadp[o * 128 + cc];
  } else if (id < 40960) {               // w0fT [64][64]
    int j = id - 36864; int o = j & 63, cc = j >> 6;
    Wf[id] = w0f[o * 64 + cc];
  } else if (id < 53248) {
    int j = id - 40960; wg0bf[j] = f2bf(wg0[j]);
  } else if (id < 65536) {
    int j = id - 53248; wg1bf[j] = f2bf(wg1[j]);
  }
}

// K0b: A0..A3 -> bf16 [4][1024][1024]
__global__ __launch_bounds__(256) void k_prep_a(
    const float* __restrict__ A0, const float* __restrict__ A1,
    const float* __restrict__ A2, const float* __restrict__ A3,
    unsigned short* __restrict__ Abf)
{
  int idx = blockIdx.x * 256 + threadIdx.x;
  int base = idx * 4;
  if (base >= 4 * 1024 * 1024) return;
  int g = base >> 20; int r = base & 1048575;
  const float* Ag = (g == 0) ? A0 : (g == 1) ? A1 : (g == 2) ? A2 : A3;
  float4 v = *reinterpret_cast<const float4*>(Ag + r);
  ushort4 o;
  o.x = f2bf(v.x); o.y = f2bf(v.y); o.z = f2bf(v.z); o.w = f2bf(v.w);
  *reinterpret_cast<ushort4*>(Abf + base) = o;
}

// ---------------------------------------------------------------------------
// K1: fused front-end, one block per (b,n):
//   dilated TC conv + relu -> xe(concat tem) -> q,k,v -> causal attn -> wo+relu
//   writes x2 bf16, layout [btl][n][64] (btl = LOCAL b*20+t within chunk)
__global__ __launch_bounds__(256) void k_front(
    const float* __restrict__ x, const float* __restrict__ tem,
    const float* __restrict__ Wf,
    const float* __restrict__ btc, const float* __restrict__ bq,
    const float* __restrict__ bk,  const float* __restrict__ bv,
    const float* __restrict__ bo,
    unsigned short* __restrict__ x2bf, int b0)
{
  __shared__ float s_x[CIN][TT];
  __shared__ float s_xe[TO][96];        // conv out (0..63) | tem (64..95)
  __shared__ float s_q[TO][64], s_k[TO][64], s_v[TO][64], s_ao[TO][64];
  const int tid = threadIdx.x;
  const int n = blockIdx.x;            // 0..1023
  const int bl = blockIdx.y;           // local batch
  const int b = b0 + bl;               // global batch
  const float* wtcT = Wf;
  const float* wqT = Wf + 6144;
  const float* wkT = Wf + 12288;
  const float* wvT = Wf + 18432;
  const float* woT = Wf + 24576;

  for (int i = tid; i < CIN * TT; i += 256) {
    int ci = i / TT, t = i % TT;
    s_x[ci][t] = x[((size_t)(b * CIN + ci) * NNODE + n) * TT + t];
  }
  for (int i = tid; i < DTEM * TO; i += 256) {
    int cj = i / TO, t = i % TO;
    s_xe[t][64 + cj] = tem[((size_t)(b * DTEM + cj) * NNODE + n) * TT + 4 + t];
  }
  __syncthreads();

  // dilated conv (dilation 2, valid) + relu. thread = (t0=tid>>6, o=tid&63), t = t0+4j
  {
    const int o = tid & 63, t0 = tid >> 6;
    float acc[5];
    float bb = btc[o];
#pragma unroll
    for (int j = 0; j < 5; ++j) acc[j] = bb;
    for (int ci = 0; ci < CIN; ++ci)
#pragma unroll
      for (int kt = 0; kt < KTAP; ++kt) {
        float w = wtcT[(ci * 3 + kt) * 64 + o];
#pragma unroll
        for (int j = 0; j < 5; ++j)
          acc[j] += s_x[ci][t0 + 4 * j + 2 * kt] * w;
      }
#pragma unroll
    for (int j = 0; j < 5; ++j) s_xe[t0 + 4 * j][o] = fmaxf(acc[j], 0.f);
  }
  __syncthreads();

  // q,k,v projections (K=96)
  {
    const int o = tid & 63, t0 = tid >> 6;
    float aq[5], ak[5], av[5];
    float vbq = bq[o], vbk = bk[o], vbv = bv[o];
#pragma unroll
    for (int j = 0; j < 5; ++j) { aq[j] = vbq; ak[j] = vbk; av[j] = vbv; }
    for (int c = 0; c < 96; ++c) {
      float wq_ = wqT[c * 64 + o], wk_ = wkT[c * 64 + o], wv_ = wvT[c * 64 + o];
#pragma unroll
      for (int j = 0; j < 5; ++j) {
        float xe = s_xe[t0 + 4 * j][c];
        aq[j] += xe * wq_; ak[j] += xe * wk_; av[j] += xe * wv_;
      }
    }
#pragma unroll
    for (int j = 0; j < 5; ++j) {
      s_q[t0 + 4 * j][o] = aq[j];
      s_k[t0 + 4 * j][o] = ak[j];
      s_v[t0 + 4 * j][o] = av[j];
    }
  }
  __syncthreads();

  // causal attention, 8 heads, head = tid>>5, t = tid&31 (lanes >= 20 idle)
  {
    const int h = tid >> 5, t = tid & 31;
    if (t < TO) {
      float qv[HD];
#pragma unroll
      for (int d = 0; d < HD; ++d) qv[d] = s_q[t][h * 8 + d];
      const float scale = 0.3535533905932738f;  // 1/sqrt(8)
      float m = -1e30f;
      for (int s = 0; s <= t; ++s) {
        float sc = 0.f;
#pragma unroll
        for (int d = 0; d < HD; ++d) sc += qv[d] * s_k[s][h * 8 + d];
        m = fmaxf(m, sc * scale);
      }
      float sum = 0.f, o[HD];
#pragma unroll
      for (int d = 0; d < HD; ++d) o[d] = 0.f;
      for (int s = 0; s <= t; ++s) {
        float sc = 0.f;
#pragma unroll
        for (int d = 0; d < HD; ++d) sc += qv[d] * s_k[s][h * 8 + d];
        float p = __expf(sc * scale - m);
        sum += p;
#pragma unroll
        for (int d = 0; d < HD; ++d) o[d] += p * s_v[s][h * 8 + d];
      }
      float inv = 1.f / sum;
#pragma unroll
      for (int d = 0; d < HD; ++d) s_ao[t][h * 8 + d] = o[d] * inv;
    }
  }
  __syncthreads();

  // wo + relu -> x2 bf16 [btl][n][64]  (LOCAL bt index)
  {
    const int o = tid & 63, t0 = tid >> 6;
    float acc[5];
    float bb = bo[o];
#pragma unroll
    for (int j = 0; j < 5; ++j) acc[j] = bb;
    for (int cc = 0; cc < 64; ++cc) {
      float w = woT[cc * 64 + o];
#pragma unroll
      for (int j = 0; j < 5; ++j) acc[j] += s_ao[t0 + 4 * j][cc] * w;
    }
#pragma unroll
    for (int j = 0; j < 5; ++j) {
      int t = t0 + 4 * j;
      x2bf[((size_t)(bl * TO + t) * NNODE + n) * 64 + o] = f2bf(fmaxf(acc[j], 0.f));
    }
  }
}

// ---------------------------------------------------------------------------
// K2: transpose x2 [btl][n][64] -> x2T [btl][64][n] (bf16), 64x64 tiles
// grid (16, NT)
__global__ __launch_bounds__(256) void k_trx2(
    const unsigned short* __restrict__ x2bf, unsigned short* __restrict__ x2t)
{
  __shared__ __align__(16) unsigned short tile[64 * 72];
  const int nb = blockIdx.x, bt = blockIdx.y;
  const int tid = threadIdx.x;
  for (int ch = tid; ch < 512; ch += 256) {
    int row = ch >> 3, seg = ch & 7;
    *reinterpret_cast<uint4*>(&tile[row * 72 + seg * 8]) =
        *reinterpret_cast<const uint4*>(x2bf + ((size_t)bt * 1024 + nb * 64 + row) * 64 + seg * 8);
  }
  __syncthreads();
  for (int ch = tid; ch < 512; ch += 256) {
    int c = ch >> 3, seg = ch & 7;
    union { unsigned short v[8]; uint4 u; } pk;
#pragma unroll
    for (int j = 0; j < 8; ++j) pk.v[j] = tile[(seg * 8 + j) * 72 + c];
    *reinterpret_cast<uint4*>(x2t + ((size_t)bt * 64 + c) * 1024 + nb * 64 + seg * 8) = pk.u;
  }
}

// ---------------------------------------------------------------------------
// K3: graph diffusion, bf16 MFMA.  Per (bt): Y[w][c] = sum_v A[w][v] * X[v][c].
// A-operand = A rows [w][v]; B-operand = X^T rows [c][v]. Tile 128(w) x 64(c), K=1024.
// grid (8*NT, 2): x = (btl<<3)|wt, y = gl (graph within pair). Abf pre-offset by gbase.
__global__ __launch_bounds__(256) void k_nconv(
    const unsigned short* __restrict__ Abf,
    const unsigned short* __restrict__ x2t,
    unsigned short* __restrict__ ybf, int NT)
{
  __shared__ __align__(16) unsigned short As[128 * 72];  // stride 72: conflict-free b128 octets
  __shared__ __align__(16) unsigned short Xs[64 * 72];
  const int wt = blockIdx.x & 7;
  const int btl = blockIdx.x >> 3;
  const int gl = blockIdx.y;
  const int tid = threadIdx.x, lane = tid & 63, wid = tid >> 6;
  const int wr = wid >> 1, wc = wid & 1;   // wave -> 64-row x 32-col quadrant
  const unsigned short* Ag = Abf + (size_t)gl * 1024 * 1024 + (size_t)wt * 128 * 1024;
  const unsigned short* Xg = x2t + (size_t)btl * 64 * 1024;

  f32x4 acc[4][2];
#pragma unroll
  for (int mi = 0; mi < 4; ++mi)
#pragma unroll
    for (int ni = 0; ni < 2; ++ni) acc[mi][ni] = f32x4{0.f, 0.f, 0.f, 0.f};

  for (int vb = 0; vb < 1024; vb += 64) {
    __syncthreads();
    for (int ch = tid; ch < 1024; ch += 256) {    // A tile 128x64
      int row = ch >> 3, seg = ch & 7;
      *reinterpret_cast<uint4*>(&As[row * 72 + seg * 8]) =
          *reinterpret_cast<const uint4*>(Ag + (size_t)row * 1024 + vb + seg * 8);
    }
    for (int ch = tid; ch < 512; ch += 256) {     // X^T tile 64x64
      int row = ch >> 3, seg = ch & 7;
      *reinterpret_cast<uint4*>(&Xs[row * 72 + seg * 8]) =
          *reinterpret_cast<const uint4*>(Xg + (size_t)row * 1024 + vb + seg * 8);
    }
    __syncthreads();
#pragma unroll
    for (int kk = 0; kk < 2; ++kk) {
      bf16x8 a[4], bfr[2];
#pragma unroll
      for (int mi = 0; mi < 4; ++mi)
        a[mi] = *reinterpret_cast<const bf16x8*>(
            &As[(wr * 64 + mi * 16 + (lane & 15)) * 72 + kk * 32 + (lane >> 4) * 8]);
#pragma unroll
      for (int ni = 0; ni < 2; ++ni)
        bfr[ni] = *reinterpret_cast<const bf16x8*>(
            &Xs[(wc * 32 + ni * 16 + (lane & 15)) * 72 + kk * 32 + (lane >> 4) * 8]);
#pragma unroll
      for (int mi = 0; mi < 4; ++mi)
#pragma unroll
        for (int ni = 0; ni < 2; ++ni)
          acc[mi][ni] = __builtin_amdgcn_mfma_f32_16x16x32_bf16(a[mi], bfr[ni], acc[mi][ni], 0, 0, 0);
    }
  }

  const size_t ybase = ((size_t)(gl * NT + btl) * 1024 + wt * 128) * 64;
#pragma unroll
  for (int mi = 0; mi < 4; ++mi)
#pragma unroll
    for (int ni = 0; ni < 2; ++ni)
#pragma unroll
      for (int rr = 0; rr < 4; ++rr) {
        int row = wr * 64 + mi * 16 + (lane >> 4) * 4 + rr;  // C/D: row=(l>>4)*4+reg
        int col = wc * 32 + ni * 16 + (lane & 15);           //      col=l&15
        ybf[ybase + (size_t)row * 64 + col] = f2bf(acc[mi][ni][rr]);
      }
}

// ---------------------------------------------------------------------------
// K4: h = relu(Wg . [x2 | y0 | y1] + bg), bf16 MFMA, K=192. One graph-pair per launch.
// grid (8*NT): x = (btl<<3)|pt. Output h bf16 [btl][n][64].
__global__ __launch_bounds__(256) void k_wg(
    const unsigned short* __restrict__ x2bf,
    const unsigned short* __restrict__ ybf,
    const unsigned short* __restrict__ wgbf,
    const float* __restrict__ bg,
    unsigned short* __restrict__ hout, int NT)
{
  __shared__ __align__(16) unsigned short As[128 * 72];
  __shared__ __align__(16) unsigned short Ws[64 * 200];   // stride 200: conflict-free
  const int pt = blockIdx.x & 7;
  const int btl = blockIdx.x >> 3;
  const int tid = threadIdx.x, lane = tid & 63, wid = tid >> 6;
  const int wr = wid >> 1, wc = wid & 1;

  for (int ch = tid; ch < 1536; ch += 256) {   // whole Wg [64][192] once
    int row = ch / 24, seg = ch % 24;
    *reinterpret_cast<uint4*>(&Ws[row * 200 + seg * 8]) =
        *reinterpret_cast<const uint4*>(wgbf + row * 192 + seg * 8);
  }

  f32x4 acc[4][2];
#pragma unroll
  for (int mi = 0; mi < 4; ++mi)
#pragma unroll
    for (int ni = 0; ni < 2; ++ni) acc[mi][ni] = f32x4{0.f, 0.f, 0.f, 0.f};

  for (int ks = 0; ks < 3; ++ks) {
    const unsigned short* src = (ks == 0)
        ? x2bf + ((size_t)btl * 1024 + pt * 128) * 64
        : ybf + (((size_t)((ks - 1) * NT + btl)) * 1024 + pt * 128) * 64;
    __syncthreads();
    for (int ch = tid; ch < 1024; ch += 256) {
      int row = ch >> 3, seg = ch & 7;
      *reinterpret_cast<uint4*>(&As[row * 72 + seg * 8]) =
          *reinterpret_cast<const uint4*>(src + (size_t)row * 64 + seg * 8);
    }
    __syncthreads();
#pragma unroll
    for (int kk = 0; kk < 2; ++kk) {
      bf16x8 a[4], bfr[2];
#pragma unroll
      for (int mi = 0; mi < 4; ++mi)
        a[mi] = *reinterpret_cast<const bf16x8*>(
            &As[(wr * 64 + mi * 16 + (lane & 15)) * 72 + kk * 32 + (lane >> 4) * 8]);
#pragma unroll
      for (int ni = 0; ni < 2; ++ni)
        bfr[ni] = *reinterpret_cast<const bf16x8*>(
            &Ws[(wc * 32 + ni * 16 + (lane & 15)) * 200 + ks * 64 + kk * 32 + (lane >> 4) * 8]);
#pragma unroll
      for (int mi = 0; mi < 4; ++mi)
#pragma unroll
        for (int ni = 0; ni < 2; ++ni)
          acc[mi][ni] = __builtin_amdgcn_mfma_f32_16x16x32_bf16(a[mi], bfr[ni], acc[mi][ni], 0, 0, 0);
    }
  }

  const size_t hbase = ((size_t)btl * 1024 + pt * 128) * 64;
#pragma unroll
  for (int mi = 0; mi < 4; ++mi)
#pragma unroll
    for (int ni = 0; ni < 2; ++ni)
#pragma unroll
      for (int rr = 0; rr < 4; ++rr) {
        int row = wr * 64 + mi * 16 + (lane >> 4) * 4 + rr;
        int col = wc * 32 + ni * 16 + (lane & 15);
        hout[hbase + (size_t)row * 64 + col] = f2bf(fmaxf(acc[mi][ni][rr] + bg[col], 0.f));
      }
}

// ---------------------------------------------------------------------------
// K5: micro-fusion + output transpose. Block = (8-node group nb, local b).
// u = wadp.[h0;h1]+b; hf_g = w0f.h_g; s_g = sum_c hf_g*u (64-lane shfl reduce);
// softmax over g; out[b][c][n][t] written directly (float4 along t).
__global__ __launch_bounds__(256) void k_fuse(
    const unsigned short* __restrict__ h0, const unsigned short* __restrict__ h1,
    const float* __restrict__ Wf, const float* __restrict__ badp,
    float* __restrict__ out, int b0)
{
  __shared__ __align__(16) unsigned short h0s[160 * 72];  // row r = nl*20+t
  __shared__ __align__(16) unsigned short h1s[160 * 72];
  const int nb = blockIdx.x;          // 0..127 (8-node group)
  const int bl = blockIdx.y;          // local b
  const int b = b0 + bl;
  const float* wadpT = Wf + 28672;
  const float* w0fT  = Wf + 36864;
  const int tid = threadIdx.x;

  for (int ch = tid; ch < 1280; ch += 256) {
    int t = ch >> 6, nl = (ch >> 3) & 7, seg = ch & 7;
    size_t src = ((size_t)(bl * 20 + t) * 1024 + nb * 8 + nl) * 64 + seg * 8;
    int r = nl * 20 + t;
    *reinterpret_cast<uint4*>(&h0s[r * 72 + seg * 8]) = *reinterpret_cast<const uint4*>(h0 + src);
    *reinterpret_cast<uint4*>(&h1s[r * 72 + seg * 8]) = *reinterpret_cast<const uint4*>(h1 + src);
  }
  __syncthreads();

  const int c = tid & 63, wid = tid >> 6;
  const float ba = badp[c];
  for (int nl_l = 0; nl_l < 2; ++nl_l) {
    const int nl = wid * 2 + nl_l;
    for (int tq = 0; tq < 5; ++tq) {
      const int r0 = nl * 20 + tq * 4;
      float u[4], f0[4], f1[4];
#pragma unroll
      for (int j = 0; j < 4; ++j) { u[j] = ba; f0[j] = 0.f; f1[j] = 0.f; }
      for (int c2 = 0; c2 < 64; ++c2) {
        float wa = wadpT[c2 * 64 + c];
        float wb = wadpT[(64 + c2) * 64 + c];
        float wf = w0fT[c2 * 64 + c];
#pragma unroll
        for (int j = 0; j < 4; ++j) {
          float a0 = bf2f(h0s[(r0 + j) * 72 + c2]);   // uniform addr -> LDS broadcast
          float a1 = bf2f(h1s[(r0 + j) * 72 + c2]);
          u[j] += a0 * wa + a1 * wb;
          f0[j] += a0 * wf;
          f1[j] += a1 * wf;
        }
      }
      float rr[4];
#pragma unroll
      for (int j = 0; j < 4; ++j) {
        float s0 = f0[j] * u[j], s1 = f1[j] * u[j];
#pragma unroll
        for (int off = 32; off > 0; off >>= 1) {
          s0 += __shfl_xor(s0, off);
          s1 += __shfl_xor(s1, off);
        }
        float m = fmaxf(s0, s1);
        float e0 = __expf(s0 - m), e1 = __expf(s1 - m);
        float a0w = e0 / (e0 + e1);
        rr[j] = a0w * f0[j] + (1.f - a0w) * f1[j];
      }
      float4 res; res.x = rr[0]; res.y = rr[1]; res.z = rr[2]; res.w = rr[3];
      *reinterpret_cast<float4*>(
          out + ((size_t)(b * 64 + c) * 1024 + nb * 8 + nl) * 20 + tq * 4) = res;
    }
  }
}

// ---------------------------------------------------------------------------
extern "C" void kernel_launch(void* const* d_in, const int* in_sizes, int n_in,
                              void* d_out, int out_size, void* d_ws, size_t ws_size,
                              hipStream_t stream) {
  (void)in_sizes; (void)n_in; (void)out_size;
  const float* x    = (const float*)d_in[0];
  const float* tem  = (const float*)d_in[1];
  const float* A0   = (const float*)d_in[2];
  const float* A1   = (const float*)d_in[3];
  const float* A2   = (const float*)d_in[4];
  const float* A3   = (const float*)d_in[5];
  const float* wtc  = (const float*)d_in[6];
  const float* btc  = (const float*)d_in[7];
  const float* wq   = (const float*)d_in[8];
  const float* bq   = (const float*)d_in[9];
  const float* wk   = (const float*)d_in[10];
  const float* bk   = (const float*)d_in[11];
  const float* wv   = (const float*)d_in[12];
  const float* bv   = (const float*)d_in[13];
  const float* wo   = (const float*)d_in[14];
  const float* bo   = (const float*)d_in[15];
  const float* wg0  = (const float*)d_in[16];
  const float* bg0  = (const float*)d_in[17];
  const float* wg1  = (const float*)d_in[18];
  const float* bg1  = (const float*)d_in[19];
  const float* wadp = (const float*)d_in[20];
  const float* badp = (const float*)d_in[21];
  const float* w0f  = (const float*)d_in[22];

  char* ws = (char*)d_ws;
  const size_t MB = (size_t)1 << 20;
  float* Wf             = (float*)(ws);                 // 163840 B
  unsigned short* wg0bf = (unsigned short*)(ws + 163840);
  unsigned short* wg1bf = (unsigned short*)(ws + 188416);
  unsigned short* Abf   = (unsigned short*)(ws + 1 * MB);  // 8 MB

  // choose batch-chunk CB so footprint = 12MB + 5*CB*2.62MB fits ws_size
  const size_t SB1 = (size_t)TO * NNODE * 64 * 2;  // 2.62 MB per batch (bf16 slab)
  int CB = 1;
  {
    const int cands[4] = {16, 8, 4, 2};
    for (int i = 0; i < 4; ++i) {
      if (12 * MB + 5 * (size_t)cands[i] * SB1 <= ws_size) { CB = cands[i]; break; }
    }
  }
  const int NT = CB * TO;
  const size_t SB = (size_t)CB * SB1;
  unsigned short* x2bf = (unsigned short*)(ws + 12 * MB);
  unsigned short* x2t  = (unsigned short*)(ws + 12 * MB + SB);
  unsigned short* ybuf = (unsigned short*)(ws + 12 * MB + 2 * SB);  // 2*SB
  unsigned short* h0   = (unsigned short*)(ws + 12 * MB + 4 * SB);
  unsigned short* h1   = x2t;  // overlay: x2T dead after 2nd nconv, h1 written after
  float* out = (float*)d_out;

  k_prep_w<<<dim3(256), dim3(256), 0, stream>>>(wtc, wq, wk, wv, wo, wadp, w0f,
                                                wg0, wg1, Wf, wg0bf, wg1bf);
  k_prep_a<<<dim3(4096), dim3(256), 0, stream>>>(A0, A1, A2, A3, Abf);

  for (int b0 = 0; b0 < BB; b0 += CB) {
    k_front<<<dim3(1024, CB), dim3(256), 0, stream>>>(x, tem, Wf, btc, bq, bk, bv, bo,
                                                      x2bf, b0);
    k_trx2<<<dim3(16, NT), dim3(256), 0, stream>>>(x2bf, x2t);
    // graphs 0,1 -> y, -> h0
    k_nconv<<<dim3(8 * NT, 2), dim3(256), 0, stream>>>(Abf, x2t, ybuf, NT);
    k_wg<<<dim3(8 * NT), dim3(256), 0, stream>>>(x2bf, ybuf, wg0bf, bg0, h0, NT);
    // graphs 2,3 -> y (reuse), -> h1 (overlays x2T)
    k_nconv<<<dim3(8 * NT, 2), dim3(256), 0, stream>>>(Abf + 2 * 1024 * 1024, x2t, ybuf, NT);
    k_wg<<<dim3(8 * NT), dim3(256), 0, stream>>>(x2bf, ybuf, wg1bf, bg1, h1, NT);
    // fusion + direct transposed store
    k_fuse<<<dim3(128, CB), dim3(256), 0, stream>>>(h0, h1, Wf, badp, out, b0);
  }
}

// Round 5
// 1363.794 us; speedup vs baseline: 1.0824x; 1.0824x over previous
//
#include <hip/hip_runtime.h>
#include <hip/hip_bf16.h>
#include <stdint.h>

// ---------------------------------------------------------------------------
constexpr int BB=16, CIN=32, CO=64, NNODE=1024, TT=24, KTAP=3, DTEM=32, NH=8, HD=8, TO=20;

typedef __attribute__((ext_vector_type(4))) float f32x4;
typedef __attribute__((ext_vector_type(8))) short bf16x8;

__device__ __forceinline__ unsigned short f2bf(float f) {
  union { float f; unsigned u; } v; v.f = f;
  unsigned r = v.u + 0x7FFFu + ((v.u >> 16) & 1u);
  return (unsigned short)(r >> 16);
}
__device__ __forceinline__ float bf2f(unsigned short s) {
  union { unsigned u; float f; } v; v.u = ((unsigned)s) << 16; return v.f;
}

// ws fixed offsets (bytes)
constexpr size_t WF_OFF    = 0;        // fp32: wadpT @ +28672 floats, w0fT @ +36864 floats
constexpr size_t WG0_OFF   = 163840;
constexpr size_t WG1_OFF   = 188416;
constexpr size_t WTCB_OFF  = 212992;   // bf16 [64][104]
constexpr size_t WQKVB_OFF = 226304;   // bf16 [192][104]
constexpr size_t WOB_OFF   = 266240;   // bf16 [64][72]
constexpr size_t ABF_OFF   = (size_t)1 << 20;   // bf16 [4][1024][1024]
constexpr size_t CHUNK0    = (size_t)12 << 20;

// ---------------------------------------------------------------------------
// K0a: weight prep (fuse fp32 transposes + all bf16 GEMM operand layouts)
__global__ __launch_bounds__(256) void k_prep_w(
    const float* __restrict__ wtc, const float* __restrict__ wq,
    const float* __restrict__ wk,  const float* __restrict__ wv,
    const float* __restrict__ wo,  const float* __restrict__ wadp,
    const float* __restrict__ w0f, const float* __restrict__ wg0,
    const float* __restrict__ wg1,
    float* __restrict__ Wf, unsigned short* __restrict__ wg0bf,
    unsigned short* __restrict__ wg1bf, unsigned short* __restrict__ wtcB,
    unsigned short* __restrict__ wqkvB, unsigned short* __restrict__ woB)
{
  int id = blockIdx.x * 256 + threadIdx.x;
  if (id < 8192) {                       // wadpT[cc*64+o] = wadp[o][cc]
    int o = id & 63, cc = id >> 6;
    Wf[28672 + id] = wadp[o * 128 + cc];
  } else if (id < 12288) {               // w0fT[cc*64+o]
    int j = id - 8192; int o = j & 63, cc = j >> 6;
    Wf[36864 + j] = w0f[o * 64 + cc];
  } else if (id < 24576) {
    int j = id - 12288; wg0bf[j] = f2bf(wg0[j]);
  } else if (id < 36864) {
    int j = id - 24576; wg1bf[j] = f2bf(wg1[j]);
  } else if (id < 43008) {               // wtcB[o][kt*32+ci] = wtc[o][ci][kt]
    int j = id - 36864; int o = j / 96, k = j % 96, kt = k >> 5, ci = k & 31;
    wtcB[o * 104 + k] = f2bf(wtc[(o * 32 + ci) * 3 + kt]);
  } else if (id < 61440) {               // wqkvB[(m*64+o)][c] rows K-contig
    int j = id - 43008; int r = j / 96, c = j % 96, m = r >> 6, o = r & 63;
    const float* w = (m == 0) ? wq : (m == 1) ? wk : wv;
    wqkvB[r * 104 + c] = f2bf(w[o * 96 + c]);
  } else if (id < 65536) {               // woB[oc][c]
    int j = id - 61440;
    woB[(j >> 6) * 72 + (j & 63)] = f2bf(wo[j]);
  }
}

// K0b: A0..A3 -> bf16 [4][1024][1024]
__global__ __launch_bounds__(256) void k_prep_a(
    const float* __restrict__ A0, const float* __restrict__ A1,
    const float* __restrict__ A2, const float* __restrict__ A3,
    unsigned short* __restrict__ Abf)
{
  int idx = blockIdx.x * 256 + threadIdx.x;
  int base = idx * 4;
  if (base >= 4 * 1024 * 1024) return;
  int g = base >> 20; int r = base & 1048575;
  const float* Ag = (g == 0) ? A0 : (g == 1) ? A1 : (g == 2) ? A2 : A3;
  float4 v = *reinterpret_cast<const float4*>(Ag + r);
  ushort4 o;
  o.x = f2bf(v.x); o.y = f2bf(v.y); o.z = f2bf(v.z); o.w = f2bf(v.w);
  *reinterpret_cast<ushort4*>(Abf + base) = o;
}

// ---------------------------------------------------------------------------
// K1: dilated conv as MFMA. Block = (ptile 0..159, bl). A-rows = 128 positions
// (pos p = n*20+t), K = 96 = kt*32+ci gathered from staged x; B = wtcB.
// Writes xe[bl][pos][96] cols 0..63 (+bias+relu); also deposits tem -> cols 64..95.
__global__ __launch_bounds__(256) void k_conv(
    const float* __restrict__ x, const float* __restrict__ tem,
    const unsigned short* __restrict__ wtcB, const float* __restrict__ btc,
    unsigned short* __restrict__ xe, int b0)
{
  __shared__ __align__(16) unsigned short Xs[8 * 24 * 40];  // [nl][t][ci], pad 40
  __shared__ __align__(16) unsigned short Ws[64 * 104];
  const int tid = threadIdx.x, lane = tid & 63, wid = tid >> 6;
  const int wr = wid >> 1, wc = wid & 1;
  const int ptile = blockIdx.x, bl = blockIdx.y, b = b0 + bl;
  const int p0 = ptile * 128, n0 = p0 / 20;

  for (int i = tid; i < 832; i += 256) {          // weights 64x104
    int row = i / 13, seg = i % 13;
    *reinterpret_cast<uint4*>(&Ws[row * 104 + seg * 8]) =
        *reinterpret_cast<const uint4*>(wtcB + row * 104 + seg * 8);
  }
  for (int i = tid; i < 6144; i += 256) {         // x stage 32ci x 8n x 24t
    int ci = i / 192, e = i % 192, nl = e / 24, t = e - nl * 24;
    int n = n0 + nl;
    float val = (n < 1024) ? x[((size_t)(b * 32 + ci) * 1024 + n) * 24 + t] : 0.f;
    Xs[(nl * 24 + t) * 40 + ci] = f2bf(val);
  }
  // tem deposit (independent of LDS): cols 64..95 of xe rows for this n-span
  for (int i = tid; i < 6144; i += 256) {
    int cj = i / 192, e = i % 192, nl = e / 24, t = e - nl * 24;
    int n = n0 + nl;
    if (t >= 4 && n < 1024) {
      float val = tem[((size_t)(b * 32 + cj) * 1024 + n) * 24 + t];
      xe[((size_t)bl * 20480 + (size_t)n * 20 + (t - 4)) * 96 + 64 + cj] = f2bf(val);
    }
  }
  __syncthreads();

  int abase[4];
#pragma unroll
  for (int mi = 0; mi < 4; ++mi) {
    int r = wr * 64 + mi * 16 + (lane & 15);
    int p = p0 + r, n = p / 20, t = p - n * 20;
    abase[mi] = ((n - n0) * 24 + t) * 40 + (lane >> 4) * 8;
  }

  f32x4 acc[4][2];
#pragma unroll
  for (int mi = 0; mi < 4; ++mi)
#pragma unroll
    for (int ni = 0; ni < 2; ++ni) acc[mi][ni] = f32x4{0.f, 0.f, 0.f, 0.f};

#pragma unroll
  for (int kk = 0; kk < 3; ++kk) {   // K-seg = kk*32 + hi*8; kt = kk (t offset 2*kk)
    bf16x8 a[4], bw[2];
#pragma unroll
    for (int mi = 0; mi < 4; ++mi)
      a[mi] = *reinterpret_cast<const bf16x8*>(&Xs[abase[mi] + kk * 80]);
#pragma unroll
    for (int ni = 0; ni < 2; ++ni)
      bw[ni] = *reinterpret_cast<const bf16x8*>(
          &Ws[(wc * 32 + ni * 16 + (lane & 15)) * 104 + kk * 32 + (lane >> 4) * 8]);
#pragma unroll
    for (int mi = 0; mi < 4; ++mi)
#pragma unroll
      for (int ni = 0; ni < 2; ++ni)
        acc[mi][ni] = __builtin_amdgcn_mfma_f32_16x16x32_bf16(a[mi], bw[ni], acc[mi][ni], 0, 0, 0);
  }

#pragma unroll
  for (int ni = 0; ni < 2; ++ni) {
    int col = wc * 32 + ni * 16 + (lane & 15);
    float bias = btc[col];
#pragma unroll
    for (int mi = 0; mi < 4; ++mi)
#pragma unroll
      for (int rr = 0; rr < 4; ++rr) {
        int row = wr * 64 + mi * 16 + (lane >> 4) * 4 + rr;
        xe[((size_t)bl * 20480 + p0 + row) * 96 + col] =
            f2bf(fmaxf(acc[mi][ni][rr] + bias, 0.f));
      }
  }
}

// ---------------------------------------------------------------------------
// K2: q,k,v projections. M=128 pos, N=192 (q|k|v), K=96. -> qkv[bl][pos][192]
__global__ __launch_bounds__(256) void k_qkv(
    const unsigned short* __restrict__ xe, const unsigned short* __restrict__ wqkvB,
    const float* __restrict__ bq, const float* __restrict__ bk,
    const float* __restrict__ bv, unsigned short* __restrict__ qkv)
{
  __shared__ __align__(16) unsigned short As[128 * 104];
  __shared__ __align__(16) unsigned short Ws[192 * 104];
  const int tid = threadIdx.x, lane = tid & 63, wid = tid >> 6;
  const int wr = wid >> 1, wc = wid & 1;
  const int ptile = blockIdx.x, bl = blockIdx.y;
  const int p0 = ptile * 128;

  for (int i = tid; i < 1536; i += 256) {
    int row = i / 12, seg = i % 12;
    *reinterpret_cast<uint4*>(&As[row * 104 + seg * 8]) =
        *reinterpret_cast<const uint4*>(xe + ((size_t)bl * 20480 + p0 + row) * 96 + seg * 8);
  }
  for (int i = tid; i < 2496; i += 256) {
    int row = i / 13, seg = i % 13;
    *reinterpret_cast<uint4*>(&Ws[row * 104 + seg * 8]) =
        *reinterpret_cast<const uint4*>(wqkvB + row * 104 + seg * 8);
  }
  __syncthreads();

  f32x4 acc[4][6];
#pragma unroll
  for (int mi = 0; mi < 4; ++mi)
#pragma unroll
    for (int ni = 0; ni < 6; ++ni) acc[mi][ni] = f32x4{0.f, 0.f, 0.f, 0.f};

#pragma unroll
  for (int kk = 0; kk < 3; ++kk) {
    bf16x8 a[4];
#pragma unroll
    for (int mi = 0; mi < 4; ++mi)
      a[mi] = *reinterpret_cast<const bf16x8*>(
          &As[(wr * 64 + mi * 16 + (lane & 15)) * 104 + kk * 32 + (lane >> 4) * 8]);
#pragma unroll
    for (int ni = 0; ni < 6; ++ni) {
      bf16x8 bw = *reinterpret_cast<const bf16x8*>(
          &Ws[(wc * 96 + ni * 16 + (lane & 15)) * 104 + kk * 32 + (lane >> 4) * 8]);
#pragma unroll
      for (int mi = 0; mi < 4; ++mi)
        acc[mi][ni] = __builtin_amdgcn_mfma_f32_16x16x32_bf16(a[mi], bw, acc[mi][ni], 0, 0, 0);
    }
  }

#pragma unroll
  for (int ni = 0; ni < 6; ++ni) {
    int c = wc * 96 + ni * 16 + (lane & 15);
    int m = c >> 6, ch = c & 63;
    float bias = (m == 0) ? bq[ch] : (m == 1) ? bk[ch] : bv[ch];
#pragma unroll
    for (int mi = 0; mi < 4; ++mi)
#pragma unroll
      for (int rr = 0; rr < 4; ++rr) {
        int row = wr * 64 + mi * 16 + (lane >> 4) * 4 + rr;
        qkv[((size_t)bl * 20480 + p0 + row) * 192 + c] = f2bf(acc[mi][ni][rr] + bias);
      }
  }
}

// ---------------------------------------------------------------------------
// K3: causal attention, register-resident online softmax.
// grid = CB*128; thread = (h=tid&7, nl=(tid>>3)&7, tq=tid>>6) -> n = nb*8+nl,
// queries t in {tq, tq+4, ..., tq+16}. Reads qkv[bl][pos][192] (L3-hot).
__global__ __launch_bounds__(256) void k_att(
    const unsigned short* __restrict__ qkv, unsigned short* __restrict__ attout)
{
  const int bx = blockIdx.x;
  const int bl = bx >> 7, nb = bx & 127;
  const int tid = threadIdx.x;
  const int h = tid & 7, nl = (tid >> 3) & 7, tq = tid >> 6;
  const int n = nb * 8 + nl;
  const unsigned short* base = qkv + ((size_t)bl * 20480 + (size_t)n * 20) * 192;
  unsigned short* obase = attout + ((size_t)bl * 20480 + (size_t)n * 20) * 64;
  const float scale = 0.3535533905932738f;

  for (int j = 0; j < 5; ++j) {
    const int t = tq + 4 * j;
    union { uint4 u; unsigned short s[8]; } qr, kr, vr, orr;
    qr.u = *reinterpret_cast<const uint4*>(base + t * 192 + h * 8);
    float q[8];
#pragma unroll
    for (int d = 0; d < 8; ++d) q[d] = bf2f(qr.s[d]) * scale;
    float m = -1e30f, l = 0.f, o[8];
#pragma unroll
    for (int d = 0; d < 8; ++d) o[d] = 0.f;
    for (int s = 0; s <= t; ++s) {
      kr.u = *reinterpret_cast<const uint4*>(base + s * 192 + 64 + h * 8);
      float sc = 0.f;
#pragma unroll
      for (int d = 0; d < 8; ++d) sc += q[d] * bf2f(kr.s[d]);
      float nm = fmaxf(m, sc);
      float w = __expf(m - nm), p = __expf(sc - nm);
      vr.u = *reinterpret_cast<const uint4*>(base + s * 192 + 128 + h * 8);
      l = l * w + p;
#pragma unroll
      for (int d = 0; d < 8; ++d) o[d] = o[d] * w + p * bf2f(vr.s[d]);
      m = nm;
    }
    float inv = 1.f / l;
#pragma unroll
    for (int d = 0; d < 8; ++d) orr.s[d] = f2bf(o[d] * inv);
    *reinterpret_cast<uint4*>(obase + t * 64 + h * 8) = orr.u;
  }
}

// ---------------------------------------------------------------------------
// K4: wo GEMM. M=128 pos, N=64, K=64, +bias+relu. Writes x2[(bl*20+t)][n][64].
__global__ __launch_bounds__(256) void k_wo(
    const unsigned short* __restrict__ attout, const unsigned short* __restrict__ woB,
    const float* __restrict__ bo, unsigned short* __restrict__ x2bf)
{
  __shared__ __align__(16) unsigned short As[128 * 72];
  __shared__ __align__(16) unsigned short Ws[64 * 72];
  const int tid = threadIdx.x, lane = tid & 63, wid = tid >> 6;
  const int wr = wid >> 1, wc = wid & 1;
  const int ptile = blockIdx.x, bl = blockIdx.y;
  const int p0 = ptile * 128;

  for (int i = tid; i < 1024; i += 256) {
    int row = i >> 3, seg = i & 7;
    *reinterpret_cast<uint4*>(&As[row * 72 + seg * 8]) =
        *reinterpret_cast<const uint4*>(attout + ((size_t)bl * 20480 + p0 + row) * 64 + seg * 8);
  }
  for (int i = tid; i < 576; i += 256) {
    int row = i / 9, seg = i % 9;
    *reinterpret_cast<uint4*>(&Ws[row * 72 + seg * 8]) =
        *reinterpret_cast<const uint4*>(woB + row * 72 + seg * 8);
  }
  __syncthreads();

  f32x4 acc[4][2];
#pragma unroll
  for (int mi = 0; mi < 4; ++mi)
#pragma unroll
    for (int ni = 0; ni < 2; ++ni) acc[mi][ni] = f32x4{0.f, 0.f, 0.f, 0.f};

#pragma unroll
  for (int kk = 0; kk < 2; ++kk) {
    bf16x8 a[4], bw[2];
#pragma unroll
    for (int mi = 0; mi < 4; ++mi)
      a[mi] = *reinterpret_cast<const bf16x8*>(
          &As[(wr * 64 + mi * 16 + (lane & 15)) * 72 + kk * 32 + (lane >> 4) * 8]);
#pragma unroll
    for (int ni = 0; ni < 2; ++ni)
      bw[ni] = *reinterpret_cast<const bf16x8*>(
          &Ws[(wc * 32 + ni * 16 + (lane & 15)) * 72 + kk * 32 + (lane >> 4) * 8]);
#pragma unroll
    for (int mi = 0; mi < 4; ++mi)
#pragma unroll
      for (int ni = 0; ni < 2; ++ni)
        acc[mi][ni] = __builtin_amdgcn_mfma_f32_16x16x32_bf16(a[mi], bw[ni], acc[mi][ni], 0, 0, 0);
  }

#pragma unroll
  for (int ni = 0; ni < 2; ++ni) {
    int col = wc * 32 + ni * 16 + (lane & 15);
    float bias = bo[col];
#pragma unroll
    for (int mi = 0; mi < 4; ++mi)
#pragma unroll
      for (int rr = 0; rr < 4; ++rr) {
        int row = wr * 64 + mi * 16 + (lane >> 4) * 4 + rr;
        int p = p0 + row, n = p / 20, t = p - n * 20;
        x2bf[((size_t)(bl * 20 + t) * 1024 + n) * 64 + col] =
            f2bf(fmaxf(acc[mi][ni][rr] + bias, 0.f));
      }
  }
}

// ---------------------------------------------------------------------------
// K5: transpose x2 [btl][n][64] -> x2T [btl][64][n]
__global__ __launch_bounds__(256) void k_trx2(
    const unsigned short* __restrict__ x2bf, unsigned short* __restrict__ x2t)
{
  __shared__ __align__(16) unsigned short tile[64 * 72];
  const int nb = blockIdx.x, bt = blockIdx.y;
  const int tid = threadIdx.x;
  for (int ch = tid; ch < 512; ch += 256) {
    int row = ch >> 3, seg = ch & 7;
    *reinterpret_cast<uint4*>(&tile[row * 72 + seg * 8]) =
        *reinterpret_cast<const uint4*>(x2bf + ((size_t)bt * 1024 + nb * 64 + row) * 64 + seg * 8);
  }
  __syncthreads();
  for (int ch = tid; ch < 512; ch += 256) {
    int c = ch >> 3, seg = ch & 7;
    union { unsigned short v[8]; uint4 u; } pk;
#pragma unroll
    for (int j = 0; j < 8; ++j) pk.v[j] = tile[(seg * 8 + j) * 72 + c];
    *reinterpret_cast<uint4*>(x2t + ((size_t)bt * 64 + c) * 1024 + nb * 64 + seg * 8) = pk.u;
  }
}

// ---------------------------------------------------------------------------
// K6: graph diffusion MFMA (verified round 2)
__global__ __launch_bounds__(256) void k_nconv(
    const unsigned short* __restrict__ Abf,
    const unsigned short* __restrict__ x2t,
    unsigned short* __restrict__ ybf, int NT)
{
  __shared__ __align__(16) unsigned short As[128 * 72];
  __shared__ __align__(16) unsigned short Xs[64 * 72];
  const int wt = blockIdx.x & 7;
  const int btl = blockIdx.x >> 3;
  const int gl = blockIdx.y;
  const int tid = threadIdx.x, lane = tid & 63, wid = tid >> 6;
  const int wr = wid >> 1, wc = wid & 1;
  const unsigned short* Ag = Abf + (size_t)gl * 1024 * 1024 + (size_t)wt * 128 * 1024;
  const unsigned short* Xg = x2t + (size_t)btl * 64 * 1024;

  f32x4 acc[4][2];
#pragma unroll
  for (int mi = 0; mi < 4; ++mi)
#pragma unroll
    for (int ni = 0; ni < 2; ++ni) acc[mi][ni] = f32x4{0.f, 0.f, 0.f, 0.f};

  for (int vb = 0; vb < 1024; vb += 64) {
    __syncthreads();
    for (int ch = tid; ch < 1024; ch += 256) {
      int row = ch >> 3, seg = ch & 7;
      *reinterpret_cast<uint4*>(&As[row * 72 + seg * 8]) =
          *reinterpret_cast<const uint4*>(Ag + (size_t)row * 1024 + vb + seg * 8);
    }
    for (int ch = tid; ch < 512; ch += 256) {
      int row = ch >> 3, seg = ch & 7;
      *reinterpret_cast<uint4*>(&Xs[row * 72 + seg * 8]) =
          *reinterpret_cast<const uint4*>(Xg + (size_t)row * 1024 + vb + seg * 8);
    }
    __syncthreads();
#pragma unroll
    for (int kk = 0; kk < 2; ++kk) {
      bf16x8 a[4], bfr[2];
#pragma unroll
      for (int mi = 0; mi < 4; ++mi)
        a[mi] = *reinterpret_cast<const bf16x8*>(
            &As[(wr * 64 + mi * 16 + (lane & 15)) * 72 + kk * 32 + (lane >> 4) * 8]);
#pragma unroll
      for (int ni = 0; ni < 2; ++ni)
        bfr[ni] = *reinterpret_cast<const bf16x8*>(
            &Xs[(wc * 32 + ni * 16 + (lane & 15)) * 72 + kk * 32 + (lane >> 4) * 8]);
#pragma unroll
      for (int mi = 0; mi < 4; ++mi)
#pragma unroll
        for (int ni = 0; ni < 2; ++ni)
          acc[mi][ni] = __builtin_amdgcn_mfma_f32_16x16x32_bf16(a[mi], bfr[ni], acc[mi][ni], 0, 0, 0);
    }
  }

  const size_t ybase = ((size_t)(gl * NT + btl) * 1024 + wt * 128) * 64;
#pragma unroll
  for (int mi = 0; mi < 4; ++mi)
#pragma unroll
    for (int ni = 0; ni < 2; ++ni)
#pragma unroll
      for (int rr = 0; rr < 4; ++rr) {
        int row = wr * 64 + mi * 16 + (lane >> 4) * 4 + rr;
        int col = wc * 32 + ni * 16 + (lane & 15);
        ybf[ybase + (size_t)row * 64 + col] = f2bf(acc[mi][ni][rr]);
      }
}

// ---------------------------------------------------------------------------
// K7: h = relu(Wg . [x2 | y0 | y1] + bg)  (verified round 2)
__global__ __launch_bounds__(256) void k_wg(
    const unsigned short* __restrict__ x2bf,
    const unsigned short* __restrict__ ybf,
    const unsigned short* __restrict__ wgbf,
    const float* __restrict__ bg,
    unsigned short* __restrict__ hout, int NT)
{
  __shared__ __align__(16) unsigned short As[128 * 72];
  __shared__ __align__(16) unsigned short Ws[64 * 200];
  const int pt = blockIdx.x & 7;
  const int btl = blockIdx.x >> 3;
  const int tid = threadIdx.x, lane = tid & 63, wid = tid >> 6;
  const int wr = wid >> 1, wc = wid & 1;

  for (int ch = tid; ch < 1536; ch += 256) {
    int row = ch / 24, seg = ch % 24;
    *reinterpret_cast<uint4*>(&Ws[row * 200 + seg * 8]) =
        *reinterpret_cast<const uint4*>(wgbf + row * 192 + seg * 8);
  }

  f32x4 acc[4][2];
#pragma unroll
  for (int mi = 0; mi < 4; ++mi)
#pragma unroll
    for (int ni = 0; ni < 2; ++ni) acc[mi][ni] = f32x4{0.f, 0.f, 0.f, 0.f};

  for (int ks = 0; ks < 3; ++ks) {
    const unsigned short* src = (ks == 0)
        ? x2bf + ((size_t)btl * 1024 + pt * 128) * 64
        : ybf + (((size_t)((ks - 1) * NT + btl)) * 1024 + pt * 128) * 64;
    __syncthreads();
    for (int ch = tid; ch < 1024; ch += 256) {
      int row = ch >> 3, seg = ch & 7;
      *reinterpret_cast<uint4*>(&As[row * 72 + seg * 8]) =
          *reinterpret_cast<const uint4*>(src + (size_t)row * 64 + seg * 8);
    }
    __syncthreads();
#pragma unroll
    for (int kk = 0; kk < 2; ++kk) {
      bf16x8 a[4], bfr[2];
#pragma unroll
      for (int mi = 0; mi < 4; ++mi)
        a[mi] = *reinterpret_cast<const bf16x8*>(
            &As[(wr * 64 + mi * 16 + (lane & 15)) * 72 + kk * 32 + (lane >> 4) * 8]);
#pragma unroll
      for (int ni = 0; ni < 2; ++ni)
        bfr[ni] = *reinterpret_cast<const bf16x8*>(
            &Ws[(wc * 32 + ni * 16 + (lane & 15)) * 200 + ks * 64 + kk * 32 + (lane >> 4) * 8]);
#pragma unroll
      for (int mi = 0; mi < 4; ++mi)
#pragma unroll
        for (int ni = 0; ni < 2; ++ni)
          acc[mi][ni] = __builtin_amdgcn_mfma_f32_16x16x32_bf16(a[mi], bfr[ni], acc[mi][ni], 0, 0, 0);
    }
  }

  const size_t hbase = ((size_t)btl * 1024 + pt * 128) * 64;
#pragma unroll
  for (int mi = 0; mi < 4; ++mi)
#pragma unroll
    for (int ni = 0; ni < 2; ++ni)
#pragma unroll
      for (int rr = 0; rr < 4; ++rr) {
        int row = wr * 64 + mi * 16 + (lane >> 4) * 4 + rr;
        int col = wc * 32 + ni * 16 + (lane & 15);
        hout[hbase + (size_t)row * 64 + col] = f2bf(fmaxf(acc[mi][ni][rr] + bg[col], 0.f));
      }
}

// ---------------------------------------------------------------------------
// K8: micro-fusion + direct transposed output store (verified round 2)
__global__ __launch_bounds__(256) void k_fuse(
    const unsigned short* __restrict__ h0, const unsigned short* __restrict__ h1,
    const float* __restrict__ Wf, const float* __restrict__ badp,
    float* __restrict__ out, int b0)
{
  __shared__ __align__(16) unsigned short h0s[160 * 72];
  __shared__ __align__(16) unsigned short h1s[160 * 72];
  const int nb = blockIdx.x;
  const int bl = blockIdx.y;
  const int b = b0 + bl;
  const float* wadpT = Wf + 28672;
  const float* w0fT  = Wf + 36864;
  const int tid = threadIdx.x;

  for (int ch = tid; ch < 1280; ch += 256) {
    int t = ch >> 6, nl = (ch >> 3) & 7, seg = ch & 7;
    size_t src = ((size_t)(bl * 20 + t) * 1024 + nb * 8 + nl) * 64 + seg * 8;
    int r = nl * 20 + t;
    *reinterpret_cast<uint4*>(&h0s[r * 72 + seg * 8]) = *reinterpret_cast<const uint4*>(h0 + src);
    *reinterpret_cast<uint4*>(&h1s[r * 72 + seg * 8]) = *reinterpret_cast<const uint4*>(h1 + src);
  }
  __syncthreads();

  const int c = tid & 63, wid = tid >> 6;
  const float ba = badp[c];
  for (int nl_l = 0; nl_l < 2; ++nl_l) {
    const int nl = wid * 2 + nl_l;
    for (int tq = 0; tq < 5; ++tq) {
      const int r0 = nl * 20 + tq * 4;
      float u[4], f0[4], f1[4];
#pragma unroll
      for (int j = 0; j < 4; ++j) { u[j] = ba; f0[j] = 0.f; f1[j] = 0.f; }
      for (int c2 = 0; c2 < 64; ++c2) {
        float wa = wadpT[c2 * 64 + c];
        float wb = wadpT[(64 + c2) * 64 + c];
        float wf = w0fT[c2 * 64 + c];
#pragma unroll
        for (int j = 0; j < 4; ++j) {
          float a0 = bf2f(h0s[(r0 + j) * 72 + c2]);
          float a1 = bf2f(h1s[(r0 + j) * 72 + c2]);
          u[j] += a0 * wa + a1 * wb;
          f0[j] += a0 * wf;
          f1[j] += a1 * wf;
        }
      }
      float rr[4];
#pragma unroll
      for (int j = 0; j < 4; ++j) {
        float s0 = f0[j] * u[j], s1 = f1[j] * u[j];
#pragma unroll
        for (int off = 32; off > 0; off >>= 1) {
          s0 += __shfl_xor(s0, off);
          s1 += __shfl_xor(s1, off);
        }
        float m = fmaxf(s0, s1);
        float e0 = __expf(s0 - m), e1 = __expf(s1 - m);
        float a0w = e0 / (e0 + e1);
        rr[j] = a0w * f0[j] + (1.f - a0w) * f1[j];
      }
      float4 res; res.x = rr[0]; res.y = rr[1]; res.z = rr[2]; res.w = rr[3];
      *reinterpret_cast<float4*>(
          out + ((size_t)(b * 64 + c) * 1024 + nb * 8 + nl) * 20 + tq * 4) = res;
    }
  }
}

// ---------------------------------------------------------------------------
extern "C" void kernel_launch(void* const* d_in, const int* in_sizes, int n_in,
                              void* d_out, int out_size, void* d_ws, size_t ws_size,
                              hipStream_t stream) {
  (void)in_sizes; (void)n_in; (void)out_size;
  const float* x    = (const float*)d_in[0];
  const float* tem  = (const float*)d_in[1];
  const float* A0   = (const float*)d_in[2];
  const float* A1   = (const float*)d_in[3];
  const float* A2   = (const float*)d_in[4];
  const float* A3   = (const float*)d_in[5];
  const float* wtc  = (const float*)d_in[6];
  const float* btc  = (const float*)d_in[7];
  const float* wq   = (const float*)d_in[8];
  const float* bq   = (const float*)d_in[9];
  const float* wk   = (const float*)d_in[10];
  const float* bk   = (const float*)d_in[11];
  const float* wv   = (const float*)d_in[12];
  const float* bv   = (const float*)d_in[13];
  const float* wo   = (const float*)d_in[14];
  const float* bo   = (const float*)d_in[15];
  const float* wg0  = (const float*)d_in[16];
  const float* bg0  = (const float*)d_in[17];
  const float* wg1  = (const float*)d_in[18];
  const float* bg1  = (const float*)d_in[19];
  const float* wadp = (const float*)d_in[20];
  const float* badp = (const float*)d_in[21];
  const float* w0f  = (const float*)d_in[22];

  char* ws = (char*)d_ws;
  float* Wf             = (float*)(ws + WF_OFF);
  unsigned short* wg0bf = (unsigned short*)(ws + WG0_OFF);
  unsigned short* wg1bf = (unsigned short*)(ws + WG1_OFF);
  unsigned short* wtcB  = (unsigned short*)(ws + WTCB_OFF);
  unsigned short* wqkvB = (unsigned short*)(ws + WQKVB_OFF);
  unsigned short* woB   = (unsigned short*)(ws + WOB_OFF);
  unsigned short* Abf   = (unsigned short*)(ws + ABF_OFF);

  // per-b slab sizes (bytes)
  const size_t SBXE = (size_t)20480 * 96 * 2;    // 3.93 MB
  const size_t SBQ  = (size_t)20480 * 192 * 2;   // 7.86 MB
  const size_t SBH  = (size_t)20480 * 64 * 2;    // 2.62 MB
  const size_t SBY  = 2 * SBH;                   // 5.24 MB (2 graphs)
  int CB = 1;
  {
    const int cands[4] = {16, 8, 4, 2};
    for (int i = 0; i < 4; ++i) {
      size_t need = CHUNK0 + (size_t)cands[i] * (SBXE + SBQ + SBY + SBH);
      if (need <= ws_size) { CB = cands[i]; break; }
    }
  }
  const int NT = CB * TO;
  const size_t XE0  = CHUNK0;
  const size_t QKV0 = XE0 + (size_t)CB * SBXE;
  const size_t Y0   = QKV0 + (size_t)CB * SBQ;
  const size_t H00  = Y0 + (size_t)CB * SBY;
  unsigned short* xebuf  = (unsigned short*)(ws + XE0);
  unsigned short* qkvbuf = (unsigned short*)(ws + QKV0);
  unsigned short* attout = (unsigned short*)(ws + XE0);            // overlay xe (dead)
  unsigned short* x2bf   = (unsigned short*)(ws + QKV0);           // overlay qkv (dead)
  unsigned short* x2t    = (unsigned short*)(ws + QKV0 + (size_t)CB * SBH);
  unsigned short* ybuf   = (unsigned short*)(ws + Y0);
  unsigned short* h0     = (unsigned short*)(ws + H00);
  unsigned short* h1     = x2t;                                    // overlay x2t (dead)
  float* out = (float*)d_out;

  k_prep_w<<<dim3(256), dim3(256), 0, stream>>>(wtc, wq, wk, wv, wo, wadp, w0f,
                                                wg0, wg1, Wf, wg0bf, wg1bf,
                                                wtcB, wqkvB, woB);
  k_prep_a<<<dim3(4096), dim3(256), 0, stream>>>(A0, A1, A2, A3, Abf);

  for (int b0 = 0; b0 < BB; b0 += CB) {
    k_conv<<<dim3(160, CB), dim3(256), 0, stream>>>(x, tem, wtcB, btc, xebuf, b0);
    k_qkv<<<dim3(160, CB), dim3(256), 0, stream>>>(xebuf, wqkvB, bq, bk, bv, qkvbuf);
    k_att<<<dim3(CB * 128), dim3(256), 0, stream>>>(qkvbuf, attout);
    k_wo<<<dim3(160, CB), dim3(256), 0, stream>>>(attout, woB, bo, x2bf);
    k_trx2<<<dim3(16, NT), dim3(256), 0, stream>>>(x2bf, x2t);
    k_nconv<<<dim3(8 * NT, 2), dim3(256), 0, stream>>>(Abf, x2t, ybuf, NT);
    k_wg<<<dim3(8 * NT), dim3(256), 0, stream>>>(x2bf, ybuf, wg0bf, bg0, h0, NT);
    k_nconv<<<dim3(8 * NT, 2), dim3(256), 0, stream>>>(Abf + 2 * 1024 * 1024, x2t, ybuf, NT);
    k_wg<<<dim3(8 * NT), dim3(256), 0, stream>>>(x2bf, ybuf, wg1bf, bg1, h1, NT);
    k_fuse<<<dim3(128, CB), dim3(256), 0, stream>>>(h0, h1, Wf, badp, out, b0);
  }
}

// Round 7
// 1118.026 us; speedup vs baseline: 1.3203x; 1.2198x over previous
//
#include <hip/hip_runtime.h>
#include <hip/hip_bf16.h>
#include <stdint.h>

// ---------------------------------------------------------------------------
constexpr int BB=16, CIN=32, CO=64, NNODE=1024, TT=24, KTAP=3, DTEM=32, NH=8, HD=8, TO=20;

typedef __attribute__((ext_vector_type(4))) float f32x4;
typedef __attribute__((ext_vector_type(8))) short bf16x8;

__device__ __forceinline__ unsigned short f2bf(float f) {
  union { float f; unsigned u; } v; v.f = f;
  unsigned r = v.u + 0x7FFFu + ((v.u >> 16) & 1u);
  return (unsigned short)(r >> 16);
}
__device__ __forceinline__ float bf2f(unsigned short s) {
  union { unsigned u; float f; } v; v.u = ((unsigned)s) << 16; return v.f;
}

// ws fixed offsets (bytes)
constexpr size_t WADPB_OFF = 0;        // bf16 [64][128] (already [o][K] for B-operand)
constexpr size_t W0FB_OFF  = 16384;    // bf16 [64][64]
constexpr size_t WG0_OFF   = 163840;
constexpr size_t WG1_OFF   = 188416;
constexpr size_t WTCB_OFF  = 212992;   // bf16 [64][104]
constexpr size_t WQKVB_OFF = 226304;   // bf16 [192][104]
constexpr size_t WOB_OFF   = 266240;   // bf16 [64][72]
constexpr size_t ABF_OFF   = (size_t)1 << 20;   // bf16 [4][1024][1024]
constexpr size_t CHUNK0    = (size_t)12 << 20;

// ---------------------------------------------------------------------------
// K0a: weight prep — all bf16 GEMM operand layouts
__global__ __launch_bounds__(256) void k_prep_w(
    const float* __restrict__ wtc, const float* __restrict__ wq,
    const float* __restrict__ wk,  const float* __restrict__ wv,
    const float* __restrict__ wo,  const float* __restrict__ wadp,
    const float* __restrict__ w0f, const float* __restrict__ wg0,
    const float* __restrict__ wg1,
    unsigned short* __restrict__ wadpB, unsigned short* __restrict__ w0fB,
    unsigned short* __restrict__ wg0bf, unsigned short* __restrict__ wg1bf,
    unsigned short* __restrict__ wtcB,  unsigned short* __restrict__ wqkvB,
    unsigned short* __restrict__ woB)
{
  int id = blockIdx.x * 256 + threadIdx.x;
  if (id < 8192) {                       // wadpB[o][cc] straight convert
    wadpB[id] = f2bf(wadp[id]);
  } else if (id < 12288) {               // w0fB[o][c2]
    int j = id - 8192; w0fB[j] = f2bf(w0f[j]);
  } else if (id < 24576) {
    int j = id - 12288; wg0bf[j] = f2bf(wg0[j]);
  } else if (id < 36864) {
    int j = id - 24576; wg1bf[j] = f2bf(wg1[j]);
  } else if (id < 43008) {               // wtcB[o][kt*32+ci] = wtc[o][ci][kt]
    int j = id - 36864; int o = j / 96, k = j % 96, kt = k >> 5, ci = k & 31;
    wtcB[o * 104 + k] = f2bf(wtc[(o * 32 + ci) * 3 + kt]);
  } else if (id < 61440) {               // wqkvB[(m*64+o)][c] rows K-contig
    int j = id - 43008; int r = j / 96, c = j % 96, m = r >> 6, o = r & 63;
    const float* w = (m == 0) ? wq : (m == 1) ? wk : wv;
    wqkvB[r * 104 + c] = f2bf(w[o * 96 + c]);
  } else if (id < 65536) {               // woB[oc][c]
    int j = id - 61440;
    woB[(j >> 6) * 72 + (j & 63)] = f2bf(wo[j]);
  }
}

// K0b: A0..A3 -> bf16 [4][1024][1024]
__global__ __launch_bounds__(256) void k_prep_a(
    const float* __restrict__ A0, const float* __restrict__ A1,
    const float* __restrict__ A2, const float* __restrict__ A3,
    unsigned short* __restrict__ Abf)
{
  int idx = blockIdx.x * 256 + threadIdx.x;
  int base = idx * 4;
  if (base >= 4 * 1024 * 1024) return;
  int g = base >> 20; int r = base & 1048575;
  const float* Ag = (g == 0) ? A0 : (g == 1) ? A1 : (g == 2) ? A2 : A3;
  float4 v = *reinterpret_cast<const float4*>(Ag + r);
  ushort4 o;
  o.x = f2bf(v.x); o.y = f2bf(v.y); o.z = f2bf(v.z); o.w = f2bf(v.w);
  *reinterpret_cast<ushort4*>(Abf + base) = o;
}

// ---------------------------------------------------------------------------
// K1: dilated conv as MFMA (verified round 5)
__global__ __launch_bounds__(256) void k_conv(
    const float* __restrict__ x, const float* __restrict__ tem,
    const unsigned short* __restrict__ wtcB, const float* __restrict__ btc,
    unsigned short* __restrict__ xe, int b0)
{
  __shared__ __align__(16) unsigned short Xs[8 * 24 * 40];
  __shared__ __align__(16) unsigned short Ws[64 * 104];
  const int tid = threadIdx.x, lane = tid & 63, wid = tid >> 6;
  const int wr = wid >> 1, wc = wid & 1;
  const int ptile = blockIdx.x, bl = blockIdx.y, b = b0 + bl;
  const int p0 = ptile * 128, n0 = p0 / 20;

  for (int i = tid; i < 832; i += 256) {
    int row = i / 13, seg = i % 13;
    *reinterpret_cast<uint4*>(&Ws[row * 104 + seg * 8]) =
        *reinterpret_cast<const uint4*>(wtcB + row * 104 + seg * 8);
  }
  for (int i = tid; i < 6144; i += 256) {
    int ci = i / 192, e = i % 192, nl = e / 24, t = e - nl * 24;
    int n = n0 + nl;
    float val = (n < 1024) ? x[((size_t)(b * 32 + ci) * 1024 + n) * 24 + t] : 0.f;
    Xs[(nl * 24 + t) * 40 + ci] = f2bf(val);
  }
  for (int i = tid; i < 6144; i += 256) {
    int cj = i / 192, e = i % 192, nl = e / 24, t = e - nl * 24;
    int n = n0 + nl;
    if (t >= 4 && n < 1024) {
      float val = tem[((size_t)(b * 32 + cj) * 1024 + n) * 24 + t];
      xe[((size_t)bl * 20480 + (size_t)n * 20 + (t - 4)) * 96 + 64 + cj] = f2bf(val);
    }
  }
  __syncthreads();

  int abase[4];
#pragma unroll
  for (int mi = 0; mi < 4; ++mi) {
    int r = wr * 64 + mi * 16 + (lane & 15);
    int p = p0 + r, n = p / 20, t = p - n * 20;
    abase[mi] = ((n - n0) * 24 + t) * 40 + (lane >> 4) * 8;
  }

  f32x4 acc[4][2];
#pragma unroll
  for (int mi = 0; mi < 4; ++mi)
#pragma unroll
    for (int ni = 0; ni < 2; ++ni) acc[mi][ni] = f32x4{0.f, 0.f, 0.f, 0.f};

#pragma unroll
  for (int kk = 0; kk < 3; ++kk) {
    bf16x8 a[4], bw[2];
#pragma unroll
    for (int mi = 0; mi < 4; ++mi)
      a[mi] = *reinterpret_cast<const bf16x8*>(&Xs[abase[mi] + kk * 80]);
#pragma unroll
    for (int ni = 0; ni < 2; ++ni)
      bw[ni] = *reinterpret_cast<const bf16x8*>(
          &Ws[(wc * 32 + ni * 16 + (lane & 15)) * 104 + kk * 32 + (lane >> 4) * 8]);
#pragma unroll
    for (int mi = 0; mi < 4; ++mi)
#pragma unroll
      for (int ni = 0; ni < 2; ++ni)
        acc[mi][ni] = __builtin_amdgcn_mfma_f32_16x16x32_bf16(a[mi], bw[ni], acc[mi][ni], 0, 0, 0);
  }

#pragma unroll
  for (int ni = 0; ni < 2; ++ni) {
    int col = wc * 32 + ni * 16 + (lane & 15);
    float bias = btc[col];
#pragma unroll
    for (int mi = 0; mi < 4; ++mi)
#pragma unroll
      for (int rr = 0; rr < 4; ++rr) {
        int row = wr * 64 + mi * 16 + (lane >> 4) * 4 + rr;
        xe[((size_t)bl * 20480 + p0 + row) * 96 + col] =
            f2bf(fmaxf(acc[mi][ni][rr] + bias, 0.f));
      }
  }
}

// ---------------------------------------------------------------------------
// K2: q,k,v projections (verified round 5)
__global__ __launch_bounds__(256) void k_qkv(
    const unsigned short* __restrict__ xe, const unsigned short* __restrict__ wqkvB,
    const float* __restrict__ bq, const float* __restrict__ bk,
    const float* __restrict__ bv, unsigned short* __restrict__ qkv)
{
  __shared__ __align__(16) unsigned short As[128 * 104];
  __shared__ __align__(16) unsigned short Ws[192 * 104];
  const int tid = threadIdx.x, lane = tid & 63, wid = tid >> 6;
  const int wr = wid >> 1, wc = wid & 1;
  const int ptile = blockIdx.x, bl = blockIdx.y;
  const int p0 = ptile * 128;

  for (int i = tid; i < 1536; i += 256) {
    int row = i / 12, seg = i % 12;
    *reinterpret_cast<uint4*>(&As[row * 104 + seg * 8]) =
        *reinterpret_cast<const uint4*>(xe + ((size_t)bl * 20480 + p0 + row) * 96 + seg * 8);
  }
  for (int i = tid; i < 2496; i += 256) {
    int row = i / 13, seg = i % 13;
    *reinterpret_cast<uint4*>(&Ws[row * 104 + seg * 8]) =
        *reinterpret_cast<const uint4*>(wqkvB + row * 104 + seg * 8);
  }
  __syncthreads();

  f32x4 acc[4][6];
#pragma unroll
  for (int mi = 0; mi < 4; ++mi)
#pragma unroll
    for (int ni = 0; ni < 6; ++ni) acc[mi][ni] = f32x4{0.f, 0.f, 0.f, 0.f};

#pragma unroll
  for (int kk = 0; kk < 3; ++kk) {
    bf16x8 a[4];
#pragma unroll
    for (int mi = 0; mi < 4; ++mi)
      a[mi] = *reinterpret_cast<const bf16x8*>(
          &As[(wr * 64 + mi * 16 + (lane & 15)) * 104 + kk * 32 + (lane >> 4) * 8]);
#pragma unroll
    for (int ni = 0; ni < 6; ++ni) {
      bf16x8 bw = *reinterpret_cast<const bf16x8*>(
          &Ws[(wc * 96 + ni * 16 + (lane & 15)) * 104 + kk * 32 + (lane >> 4) * 8]);
#pragma unroll
      for (int mi = 0; mi < 4; ++mi)
        acc[mi][ni] = __builtin_amdgcn_mfma_f32_16x16x32_bf16(a[mi], bw, acc[mi][ni], 0, 0, 0);
    }
  }

#pragma unroll
  for (int ni = 0; ni < 6; ++ni) {
    int c = wc * 96 + ni * 16 + (lane & 15);
    int m = c >> 6, ch = c & 63;
    float bias = (m == 0) ? bq[ch] : (m == 1) ? bk[ch] : bv[ch];
#pragma unroll
    for (int mi = 0; mi < 4; ++mi)
#pragma unroll
      for (int rr = 0; rr < 4; ++rr) {
        int row = wr * 64 + mi * 16 + (lane >> 4) * 4 + rr;
        qkv[((size_t)bl * 20480 + p0 + row) * 192 + c] = f2bf(acc[mi][ni][rr] + bias);
      }
  }
}

// ---------------------------------------------------------------------------
// K3: causal attention (verified round 5)
__global__ __launch_bounds__(256) void k_att(
    const unsigned short* __restrict__ qkv, unsigned short* __restrict__ attout)
{
  const int bx = blockIdx.x;
  const int bl = bx >> 7, nb = bx & 127;
  const int tid = threadIdx.x;
  const int h = tid & 7, nl = (tid >> 3) & 7, tq = tid >> 6;
  const int n = nb * 8 + nl;
  const unsigned short* base = qkv + ((size_t)bl * 20480 + (size_t)n * 20) * 192;
  unsigned short* obase = attout + ((size_t)bl * 20480 + (size_t)n * 20) * 64;
  const float scale = 0.3535533905932738f;

  for (int j = 0; j < 5; ++j) {
    const int t = tq + 4 * j;
    union { uint4 u; unsigned short s[8]; } qr, kr, vr, orr;
    qr.u = *reinterpret_cast<const uint4*>(base + t * 192 + h * 8);
    float q[8];
#pragma unroll
    for (int d = 0; d < 8; ++d) q[d] = bf2f(qr.s[d]) * scale;
    float m = -1e30f, l = 0.f, o[8];
#pragma unroll
    for (int d = 0; d < 8; ++d) o[d] = 0.f;
    for (int s = 0; s <= t; ++s) {
      kr.u = *reinterpret_cast<const uint4*>(base + s * 192 + 64 + h * 8);
      float sc = 0.f;
#pragma unroll
      for (int d = 0; d < 8; ++d) sc += q[d] * bf2f(kr.s[d]);
      float nm = fmaxf(m, sc);
      float w = __expf(m - nm), p = __expf(sc - nm);
      vr.u = *reinterpret_cast<const uint4*>(base + s * 192 + 128 + h * 8);
      l = l * w + p;
#pragma unroll
      for (int d = 0; d < 8; ++d) o[d] = o[d] * w + p * bf2f(vr.s[d]);
      m = nm;
    }
    float inv = 1.f / l;
#pragma unroll
    for (int d = 0; d < 8; ++d) orr.s[d] = f2bf(o[d] * inv);
    *reinterpret_cast<uint4*>(obase + t * 64 + h * 8) = orr.u;
  }
}

// ---------------------------------------------------------------------------
// K4: wo GEMM (verified round 5)
__global__ __launch_bounds__(256) void k_wo(
    const unsigned short* __restrict__ attout, const unsigned short* __restrict__ woB,
    const float* __restrict__ bo, unsigned short* __restrict__ x2bf)
{
  __shared__ __align__(16) unsigned short As[128 * 72];
  __shared__ __align__(16) unsigned short Ws[64 * 72];
  const int tid = threadIdx.x, lane = tid & 63, wid = tid >> 6;
  const int wr = wid >> 1, wc = wid & 1;
  const int ptile = blockIdx.x, bl = blockIdx.y;
  const int p0 = ptile * 128;

  for (int i = tid; i < 1024; i += 256) {
    int row = i >> 3, seg = i & 7;
    *reinterpret_cast<uint4*>(&As[row * 72 + seg * 8]) =
        *reinterpret_cast<const uint4*>(attout + ((size_t)bl * 20480 + p0 + row) * 64 + seg * 8);
  }
  for (int i = tid; i < 576; i += 256) {
    int row = i / 9, seg = i % 9;
    *reinterpret_cast<uint4*>(&Ws[row * 72 + seg * 8]) =
        *reinterpret_cast<const uint4*>(woB + row * 72 + seg * 8);
  }
  __syncthreads();

  f32x4 acc[4][2];
#pragma unroll
  for (int mi = 0; mi < 4; ++mi)
#pragma unroll
    for (int ni = 0; ni < 2; ++ni) acc[mi][ni] = f32x4{0.f, 0.f, 0.f, 0.f};

#pragma unroll
  for (int kk = 0; kk < 2; ++kk) {
    bf16x8 a[4], bw[2];
#pragma unroll
    for (int mi = 0; mi < 4; ++mi)
      a[mi] = *reinterpret_cast<const bf16x8*>(
          &As[(wr * 64 + mi * 16 + (lane & 15)) * 72 + kk * 32 + (lane >> 4) * 8]);
#pragma unroll
    for (int ni = 0; ni < 2; ++ni)
      bw[ni] = *reinterpret_cast<const bf16x8*>(
          &Ws[(wc * 32 + ni * 16 + (lane & 15)) * 72 + kk * 32 + (lane >> 4) * 8]);
#pragma unroll
    for (int mi = 0; mi < 4; ++mi)
#pragma unroll
      for (int ni = 0; ni < 2; ++ni)
        acc[mi][ni] = __builtin_amdgcn_mfma_f32_16x16x32_bf16(a[mi], bw[ni], acc[mi][ni], 0, 0, 0);
  }

#pragma unroll
  for (int ni = 0; ni < 2; ++ni) {
    int col = wc * 32 + ni * 16 + (lane & 15);
    float bias = bo[col];
#pragma unroll
    for (int mi = 0; mi < 4; ++mi)
#pragma unroll
      for (int rr = 0; rr < 4; ++rr) {
        int row = wr * 64 + mi * 16 + (lane >> 4) * 4 + rr;
        int p = p0 + row, n = p / 20, t = p - n * 20;
        x2bf[((size_t)(bl * 20 + t) * 1024 + n) * 64 + col] =
            f2bf(fmaxf(acc[mi][ni][rr] + bias, 0.f));
      }
  }
}

// ---------------------------------------------------------------------------
// K5: transpose x2 [btl][n][64] -> x2T [btl][64][n]
__global__ __launch_bounds__(256) void k_trx2(
    const unsigned short* __restrict__ x2bf, unsigned short* __restrict__ x2t)
{
  __shared__ __align__(16) unsigned short tile[64 * 72];
  const int nb = blockIdx.x, bt = blockIdx.y;
  const int tid = threadIdx.x;
  for (int ch = tid; ch < 512; ch += 256) {
    int row = ch >> 3, seg = ch & 7;
    *reinterpret_cast<uint4*>(&tile[row * 72 + seg * 8]) =
        *reinterpret_cast<const uint4*>(x2bf + ((size_t)bt * 1024 + nb * 64 + row) * 64 + seg * 8);
  }
  __syncthreads();
  for (int ch = tid; ch < 512; ch += 256) {
    int c = ch >> 3, seg = ch & 7;
    union { unsigned short v[8]; uint4 u; } pk;
#pragma unroll
    for (int j = 0; j < 8; ++j) pk.v[j] = tile[(seg * 8 + j) * 72 + c];
    *reinterpret_cast<uint4*>(x2t + ((size_t)bt * 64 + c) * 1024 + nb * 64 + seg * 8) = pk.u;
  }
}

// ---------------------------------------------------------------------------
// K6: graph diffusion MFMA (verified round 2)
__global__ __launch_bounds__(256) void k_nconv(
    const unsigned short* __restrict__ Abf,
    const unsigned short* __restrict__ x2t,
    unsigned short* __restrict__ ybf, int NT)
{
  __shared__ __align__(16) unsigned short As[128 * 72];
  __shared__ __align__(16) unsigned short Xs[64 * 72];
  const int wt = blockIdx.x & 7;
  const int btl = blockIdx.x >> 3;
  const int gl = blockIdx.y;
  const int tid = threadIdx.x, lane = tid & 63, wid = tid >> 6;
  const int wr = wid >> 1, wc = wid & 1;
  const unsigned short* Ag = Abf + (size_t)gl * 1024 * 1024 + (size_t)wt * 128 * 1024;
  const unsigned short* Xg = x2t + (size_t)btl * 64 * 1024;

  f32x4 acc[4][2];
#pragma unroll
  for (int mi = 0; mi < 4; ++mi)
#pragma unroll
    for (int ni = 0; ni < 2; ++ni) acc[mi][ni] = f32x4{0.f, 0.f, 0.f, 0.f};

  for (int vb = 0; vb < 1024; vb += 64) {
    __syncthreads();
    for (int ch = tid; ch < 1024; ch += 256) {
      int row = ch >> 3, seg = ch & 7;
      *reinterpret_cast<uint4*>(&As[row * 72 + seg * 8]) =
          *reinterpret_cast<const uint4*>(Ag + (size_t)row * 1024 + vb + seg * 8);
    }
    for (int ch = tid; ch < 512; ch += 256) {
      int row = ch >> 3, seg = ch & 7;
      *reinterpret_cast<uint4*>(&Xs[row * 72 + seg * 8]) =
          *reinterpret_cast<const uint4*>(Xg + (size_t)row * 1024 + vb + seg * 8);
    }
    __syncthreads();
#pragma unroll
    for (int kk = 0; kk < 2; ++kk) {
      bf16x8 a[4], bfr[2];
#pragma unroll
      for (int mi = 0; mi < 4; ++mi)
        a[mi] = *reinterpret_cast<const bf16x8*>(
            &As[(wr * 64 + mi * 16 + (lane & 15)) * 72 + kk * 32 + (lane >> 4) * 8]);
#pragma unroll
      for (int ni = 0; ni < 2; ++ni)
        bfr[ni] = *reinterpret_cast<const bf16x8*>(
            &Xs[(wc * 32 + ni * 16 + (lane & 15)) * 72 + kk * 32 + (lane >> 4) * 8]);
#pragma unroll
      for (int mi = 0; mi < 4; ++mi)
#pragma unroll
        for (int ni = 0; ni < 2; ++ni)
          acc[mi][ni] = __builtin_amdgcn_mfma_f32_16x16x32_bf16(a[mi], bfr[ni], acc[mi][ni], 0, 0, 0);
    }
  }

  const size_t ybase = ((size_t)(gl * NT + btl) * 1024 + wt * 128) * 64;
#pragma unroll
  for (int mi = 0; mi < 4; ++mi)
#pragma unroll
    for (int ni = 0; ni < 2; ++ni)
#pragma unroll
      for (int rr = 0; rr < 4; ++rr) {
        int row = wr * 64 + mi * 16 + (lane >> 4) * 4 + rr;
        int col = wc * 32 + ni * 16 + (lane & 15);
        ybf[ybase + (size_t)row * 64 + col] = f2bf(acc[mi][ni][rr]);
      }
}

// ---------------------------------------------------------------------------
// K7: h = relu(Wg . [x2 | y0 | y1] + bg)  (verified round 2)
__global__ __launch_bounds__(256) void k_wg(
    const unsigned short* __restrict__ x2bf,
    const unsigned short* __restrict__ ybf,
    const unsigned short* __restrict__ wgbf,
    const float* __restrict__ bg,
    unsigned short* __restrict__ hout, int NT)
{
  __shared__ __align__(16) unsigned short As[128 * 72];
  __shared__ __align__(16) unsigned short Ws[64 * 200];
  const int pt = blockIdx.x & 7;
  const int btl = blockIdx.x >> 3;
  const int tid = threadIdx.x, lane = tid & 63, wid = tid >> 6;
  const int wr = wid >> 1, wc = wid & 1;

  for (int ch = tid; ch < 1536; ch += 256) {
    int row = ch / 24, seg = ch % 24;
    *reinterpret_cast<uint4*>(&Ws[row * 200 + seg * 8]) =
        *reinterpret_cast<const uint4*>(wgbf + row * 192 + seg * 8);
  }

  f32x4 acc[4][2];
#pragma unroll
  for (int mi = 0; mi < 4; ++mi)
#pragma unroll
    for (int ni = 0; ni < 2; ++ni) acc[mi][ni] = f32x4{0.f, 0.f, 0.f, 0.f};

  for (int ks = 0; ks < 3; ++ks) {
    const unsigned short* src = (ks == 0)
        ? x2bf + ((size_t)btl * 1024 + pt * 128) * 64
        : ybf + (((size_t)((ks - 1) * NT + btl)) * 1024 + pt * 128) * 64;
    __syncthreads();
    for (int ch = tid; ch < 1024; ch += 256) {
      int row = ch >> 3, seg = ch & 7;
      *reinterpret_cast<uint4*>(&As[row * 72 + seg * 8]) =
          *reinterpret_cast<const uint4*>(src + (size_t)row * 64 + seg * 8);
    }
    __syncthreads();
#pragma unroll
    for (int kk = 0; kk < 2; ++kk) {
      bf16x8 a[4], bfr[2];
#pragma unroll
      for (int mi = 0; mi < 4; ++mi)
        a[mi] = *reinterpret_cast<const bf16x8*>(
            &As[(wr * 64 + mi * 16 + (lane & 15)) * 72 + kk * 32 + (lane >> 4) * 8]);
#pragma unroll
      for (int ni = 0; ni < 2; ++ni)
        bfr[ni] = *reinterpret_cast<const bf16x8*>(
            &Ws[(wc * 32 + ni * 16 + (lane & 15)) * 200 + ks * 64 + kk * 32 + (lane >> 4) * 8]);
#pragma unroll
      for (int mi = 0; mi < 4; ++mi)
#pragma unroll
        for (int ni = 0; ni < 2; ++ni)
          acc[mi][ni] = __builtin_amdgcn_mfma_f32_16x16x32_bf16(a[mi], bfr[ni], acc[mi][ni], 0, 0, 0);
    }
  }

  const size_t hbase = ((size_t)btl * 1024 + pt * 128) * 64;
#pragma unroll
  for (int mi = 0; mi < 4; ++mi)
#pragma unroll
    for (int ni = 0; ni < 2; ++ni)
#pragma unroll
      for (int rr = 0; rr < 4; ++rr) {
        int row = wr * 64 + mi * 16 + (lane >> 4) * 4 + rr;
        int col = wc * 32 + ni * 16 + (lane & 15);
        hout[hbase + (size_t)row * 64 + col] = f2bf(fmaxf(acc[mi][ni][rr] + bg[col], 0.f));
      }
}

// ---------------------------------------------------------------------------
// K8: micro-fusion via MFMA. Block = (ntile 0..7, btl). M=128 n's, N=64 c.
// U = [h0|h1].wadp^T (K=128), F0 = h0.w0f^T, F1 = h1.w0f^T (K=64; A-frags shared
// with U's kk halves). Epilogue: s_g = sum_c F_g*(U+badp) via in-reg ni-sum +
// 16-lane shfl_xor; softmax over g; res -> otmp[btl][n][64] fp32 contiguous.
__global__ __launch_bounds__(256) void k_fuse2(
    const unsigned short* __restrict__ h0, const unsigned short* __restrict__ h1,
    const unsigned short* __restrict__ wadpB, const unsigned short* __restrict__ w0fB,
    const float* __restrict__ badp, float* __restrict__ otmp)
{
  __shared__ __align__(16) unsigned short As[128 * 136];  // [n-row][h0(64)|h1(64)], pad 136
  __shared__ __align__(16) unsigned short Bs[64 * 136];   // wadp rows [o][128]
  __shared__ __align__(16) unsigned short Cs[64 * 72];    // w0f rows [o][64]
  const int ntile = blockIdx.x, btl = blockIdx.y;
  const int n0 = ntile * 128;
  const int tid = threadIdx.x, lane = tid & 63, wid = tid >> 6;

  for (int ch = tid; ch < 2048; ch += 256) {
    int half = ch >> 10, r = (ch >> 3) & 127, seg = ch & 7;
    const unsigned short* src = half ? h1 : h0;
    *reinterpret_cast<uint4*>(&As[r * 136 + half * 64 + seg * 8]) =
        *reinterpret_cast<const uint4*>(src + ((size_t)btl * 1024 + n0 + r) * 64 + seg * 8);
  }
  for (int ch = tid; ch < 1024; ch += 256) {
    int r = ch >> 4, seg = ch & 15;
    *reinterpret_cast<uint4*>(&Bs[r * 136 + seg * 8]) =
        *reinterpret_cast<const uint4*>(wadpB + r * 128 + seg * 8);
  }
  for (int ch = tid; ch < 512; ch += 256) {
    int r = ch >> 3, seg = ch & 7;
    *reinterpret_cast<uint4*>(&Cs[r * 72 + seg * 8]) =
        *reinterpret_cast<const uint4*>(w0fB + r * 64 + seg * 8);
  }
  __syncthreads();

  // wave = 32 rows x all 64 cols
  f32x4 aU[2][4], aF0[2][4], aF1[2][4];
#pragma unroll
  for (int mi = 0; mi < 2; ++mi)
#pragma unroll
    for (int ni = 0; ni < 4; ++ni) {
      aU[mi][ni] = f32x4{0.f, 0.f, 0.f, 0.f};
      aF0[mi][ni] = f32x4{0.f, 0.f, 0.f, 0.f};
      aF1[mi][ni] = f32x4{0.f, 0.f, 0.f, 0.f};
    }

  bf16x8 a[2][4];
#pragma unroll
  for (int mi = 0; mi < 2; ++mi)
#pragma unroll
    for (int kk = 0; kk < 4; ++kk)
      a[mi][kk] = *reinterpret_cast<const bf16x8*>(
          &As[(wid * 32 + mi * 16 + (lane & 15)) * 136 + kk * 32 + (lane >> 4) * 8]);

#pragma unroll
  for (int kk = 0; kk < 4; ++kk)
#pragma unroll
    for (int ni = 0; ni < 4; ++ni) {
      bf16x8 bw = *reinterpret_cast<const bf16x8*>(
          &Bs[(ni * 16 + (lane & 15)) * 136 + kk * 32 + (lane >> 4) * 8]);
#pragma unroll
      for (int mi = 0; mi < 2; ++mi)
        aU[mi][ni] = __builtin_amdgcn_mfma_f32_16x16x32_bf16(a[mi][kk], bw, aU[mi][ni], 0, 0, 0);
    }
#pragma unroll
  for (int kk = 0; kk < 2; ++kk)
#pragma unroll
    for (int ni = 0; ni < 4; ++ni) {
      bf16x8 cw = *reinterpret_cast<const bf16x8*>(
          &Cs[(ni * 16 + (lane & 15)) * 72 + kk * 32 + (lane >> 4) * 8]);
#pragma unroll
      for (int mi = 0; mi < 2; ++mi) {
        aF0[mi][ni] = __builtin_amdgcn_mfma_f32_16x16x32_bf16(a[mi][kk], cw, aF0[mi][ni], 0, 0, 0);
        aF1[mi][ni] = __builtin_amdgcn_mfma_f32_16x16x32_bf16(a[mi][kk + 2], cw, aF1[mi][ni], 0, 0, 0);
      }
    }

  float bcol[4];
#pragma unroll
  for (int ni = 0; ni < 4; ++ni) bcol[ni] = badp[ni * 16 + (lane & 15)];

#pragma unroll
  for (int mi = 0; mi < 2; ++mi)
#pragma unroll
    for (int rr = 0; rr < 4; ++rr) {
      float s0 = 0.f, s1 = 0.f;
#pragma unroll
      for (int ni = 0; ni < 4; ++ni) {
        float u = aU[mi][ni][rr] + bcol[ni];
        s0 += aF0[mi][ni][rr] * u;
        s1 += aF1[mi][ni][rr] * u;
      }
#pragma unroll
      for (int off = 1; off < 16; off <<= 1) {   // reduce over 16 col-lanes (l&15)
        s0 += __shfl_xor(s0, off);
        s1 += __shfl_xor(s1, off);
      }
      float mmax = fmaxf(s0, s1);
      float e0 = __expf(s0 - mmax), e1 = __expf(s1 - mmax);
      float a0w = e0 / (e0 + e1);
      int row = wid * 32 + mi * 16 + (lane >> 4) * 4 + rr;
      size_t base = ((size_t)btl * 1024 + n0 + row) * 64;
#pragma unroll
      for (int ni = 0; ni < 4; ++ni)
        otmp[base + ni * 16 + (lane & 15)] =
            a0w * aF0[mi][ni][rr] + (1.f - a0w) * aF1[mi][ni][rr];
    }
}

// ---------------------------------------------------------------------------
// K9: otmp [btl][n][64] fp32 -> out [b][c][n][t], full-line stores (640B runs).
__global__ __launch_bounds__(256) void k_otr(
    const float* __restrict__ otmp, float* __restrict__ out, int b0)
{
  __shared__ __align__(16) float tile[160 * 68];   // [nl*20+t][c], pad 68
  const int nb = blockIdx.x;           // 0..127 (8-node group)
  const int bl = blockIdx.y;
  const int b = b0 + bl;
  const int tid = threadIdx.x;

  for (int ch = tid; ch < 2560; ch += 256) {
    int t = ch >> 7, rem = ch & 127, nl = rem >> 4, seg = rem & 15;
    *reinterpret_cast<float4*>(&tile[(nl * 20 + t) * 68 + seg * 4]) =
        *reinterpret_cast<const float4*>(
            otmp + ((size_t)(bl * 20 + t) * 1024 + nb * 8 + nl) * 64 + seg * 4);
  }
  __syncthreads();
  for (int ch = tid; ch < 2560; ch += 256) {
    int tq = ch % 5, pair = ch / 5;
    int nl = pair & 7, cc = pair >> 3;
    float4 v;
    v.x = tile[(nl * 20 + tq * 4 + 0) * 68 + cc];
    v.y = tile[(nl * 20 + tq * 4 + 1) * 68 + cc];
    v.z = tile[(nl * 20 + tq * 4 + 2) * 68 + cc];
    v.w = tile[(nl * 20 + tq * 4 + 3) * 68 + cc];
    *reinterpret_cast<float4*>(
        out + ((size_t)(b * 64 + cc) * 1024 + nb * 8 + nl) * 20 + tq * 4) = v;
  }
}

// ---------------------------------------------------------------------------
extern "C" void kernel_launch(void* const* d_in, const int* in_sizes, int n_in,
                              void* d_out, int out_size, void* d_ws, size_t ws_size,
                              hipStream_t stream) {
  (void)in_sizes; (void)n_in; (void)out_size;
  const float* x    = (const float*)d_in[0];
  const float* tem  = (const float*)d_in[1];
  const float* A0   = (const float*)d_in[2];
  const float* A1   = (const float*)d_in[3];
  const float* A2   = (const float*)d_in[4];
  const float* A3   = (const float*)d_in[5];
  const float* wtc  = (const float*)d_in[6];
  const float* btc  = (const float*)d_in[7];
  const float* wq   = (const float*)d_in[8];
  const float* bq   = (const float*)d_in[9];
  const float* wk   = (const float*)d_in[10];
  const float* bk   = (const float*)d_in[11];
  const float* wv   = (const float*)d_in[12];
  const float* bv   = (const float*)d_in[13];
  const float* wo   = (const float*)d_in[14];
  const float* bo   = (const float*)d_in[15];
  const float* wg0  = (const float*)d_in[16];
  const float* bg0  = (const float*)d_in[17];
  const float* wg1  = (const float*)d_in[18];
  const float* bg1  = (const float*)d_in[19];
  const float* wadp = (const float*)d_in[20];
  const float* badp = (const float*)d_in[21];
  const float* w0f  = (const float*)d_in[22];

  char* ws = (char*)d_ws;
  unsigned short* wadpB = (unsigned short*)(ws + WADPB_OFF);
  unsigned short* w0fB  = (unsigned short*)(ws + W0FB_OFF);
  unsigned short* wg0bf = (unsigned short*)(ws + WG0_OFF);
  unsigned short* wg1bf = (unsigned short*)(ws + WG1_OFF);
  unsigned short* wtcB  = (unsigned short*)(ws + WTCB_OFF);
  unsigned short* wqkvB = (unsigned short*)(ws + WQKVB_OFF);
  unsigned short* woB   = (unsigned short*)(ws + WOB_OFF);
  unsigned short* Abf   = (unsigned short*)(ws + ABF_OFF);

  // per-b slab sizes (bytes)
  const size_t SBXE = (size_t)20480 * 96 * 2;    // 3.93 MB
  const size_t SBQ  = (size_t)20480 * 192 * 2;   // 7.86 MB
  const size_t SBH  = (size_t)20480 * 64 * 2;    // 2.62 MB
  const size_t SBY  = 2 * SBH;                   // 5.24 MB (2 graphs / otmp fp32)
  int CB = 1;
  {
    const int cands[4] = {16, 8, 4, 2};
    for (int i = 0; i < 4; ++i) {
      size_t need = CHUNK0 + (size_t)cands[i] * (SBXE + SBQ + SBY + SBH);
      if (need <= ws_size) { CB = cands[i]; break; }
    }
  }
  const int NT = CB * TO;
  const size_t XE0  = CHUNK0;
  const size_t QKV0 = XE0 + (size_t)CB * SBXE;
  const size_t Y0   = QKV0 + (size_t)CB * SBQ;
  const size_t H00  = Y0 + (size_t)CB * SBY;
  unsigned short* xebuf  = (unsigned short*)(ws + XE0);
  unsigned short* qkvbuf = (unsigned short*)(ws + QKV0);
  unsigned short* attout = (unsigned short*)(ws + XE0);            // overlay xe (dead)
  unsigned short* x2bf   = (unsigned short*)(ws + QKV0);           // overlay qkv (dead)
  unsigned short* x2t    = (unsigned short*)(ws + QKV0 + (size_t)CB * SBH);
  unsigned short* ybuf   = (unsigned short*)(ws + Y0);
  unsigned short* h0     = (unsigned short*)(ws + H00);
  unsigned short* h1     = x2t;                                    // overlay x2t (dead)
  float* otmp            = (float*)(ws + Y0);                      // overlay ybuf (dead), CB*SBY bytes
  float* out = (float*)d_out;

  k_prep_w<<<dim3(256), dim3(256), 0, stream>>>(wtc, wq, wk, wv, wo, wadp, w0f,
                                                wg0, wg1, wadpB, w0fB, wg0bf, wg1bf,
                                                wtcB, wqkvB, woB);
  k_prep_a<<<dim3(4096), dim3(256), 0, stream>>>(A0, A1, A2, A3, Abf);

  for (int b0 = 0; b0 < BB; b0 += CB) {
    k_conv<<<dim3(160, CB), dim3(256), 0, stream>>>(x, tem, wtcB, btc, xebuf, b0);
    k_qkv<<<dim3(160, CB), dim3(256), 0, stream>>>(xebuf, wqkvB, bq, bk, bv, qkvbuf);
    k_att<<<dim3(CB * 128), dim3(256), 0, stream>>>(qkvbuf, attout);
    k_wo<<<dim3(160, CB), dim3(256), 0, stream>>>(attout, woB, bo, x2bf);
    k_trx2<<<dim3(16, NT), dim3(256), 0, stream>>>(x2bf, x2t);
    k_nconv<<<dim3(8 * NT, 2), dim3(256), 0, stream>>>(Abf, x2t, ybuf, NT);
    k_wg<<<dim3(8 * NT), dim3(256), 0, stream>>>(x2bf, ybuf, wg0bf, bg0, h0, NT);
    k_nconv<<<dim3(8 * NT, 2), dim3(256), 0, stream>>>(Abf + 2 * 1024 * 1024, x2t, ybuf, NT);
    k_wg<<<dim3(8 * NT), dim3(256), 0, stream>>>(x2bf, ybuf, wg1bf, bg1, h1, NT);
    k_fuse2<<<dim3(8, NT), dim3(256), 0, stream>>>(h0, h1, wadpB, w0fB, badp, otmp);
    k_otr<<<dim3(128, CB), dim3(256), 0, stream>>>(otmp, out, b0);
  }
}

// Round 8
// 993.343 us; speedup vs baseline: 1.4860x; 1.1255x over previous
//
#include <hip/hip_runtime.h>
#include <hip/hip_bf16.h>
#include <stdint.h>

// ---------------------------------------------------------------------------
constexpr int BB=16, CIN=32, CO=64, NNODE=1024, TT=24, KTAP=3, DTEM=32, NH=8, HD=8, TO=20;

typedef __attribute__((ext_vector_type(4))) float f32x4;
typedef __attribute__((ext_vector_type(8))) short bf16x8;

__device__ __forceinline__ unsigned short f2bf(float f) {
  union { float f; unsigned u; } v; v.f = f;
  unsigned r = v.u + 0x7FFFu + ((v.u >> 16) & 1u);
  return (unsigned short)(r >> 16);
}
__device__ __forceinline__ float bf2f(unsigned short s) {
  union { unsigned u; float f; } v; v.u = ((unsigned)s) << 16; return v.f;
}

// ws fixed offsets (bytes)
constexpr size_t WADPB_OFF = 0;        // bf16 [64][128]
constexpr size_t W0FB_OFF  = 16384;    // bf16 [64][64]
constexpr size_t WG0_OFF   = 163840;
constexpr size_t WG1_OFF   = 188416;
constexpr size_t WTCB_OFF  = 212992;   // bf16 [64][104]
constexpr size_t WQKVB_OFF = 226304;   // bf16 [192][104]
constexpr size_t WOB_OFF   = 266240;   // bf16 [64][72]
constexpr size_t ABF_OFF   = (size_t)1 << 20;   // bf16 [4][1024][1024]
constexpr size_t CHUNK0    = (size_t)12 << 20;

// ---------------------------------------------------------------------------
// K0a: weight prep (verified round 7)
__global__ __launch_bounds__(256) void k_prep_w(
    const float* __restrict__ wtc, const float* __restrict__ wq,
    const float* __restrict__ wk,  const float* __restrict__ wv,
    const float* __restrict__ wo,  const float* __restrict__ wadp,
    const float* __restrict__ w0f, const float* __restrict__ wg0,
    const float* __restrict__ wg1,
    unsigned short* __restrict__ wadpB, unsigned short* __restrict__ w0fB,
    unsigned short* __restrict__ wg0bf, unsigned short* __restrict__ wg1bf,
    unsigned short* __restrict__ wtcB,  unsigned short* __restrict__ wqkvB,
    unsigned short* __restrict__ woB)
{
  int id = blockIdx.x * 256 + threadIdx.x;
  if (id < 8192) {
    wadpB[id] = f2bf(wadp[id]);
  } else if (id < 12288) {
    int j = id - 8192; w0fB[j] = f2bf(w0f[j]);
  } else if (id < 24576) {
    int j = id - 12288; wg0bf[j] = f2bf(wg0[j]);
  } else if (id < 36864) {
    int j = id - 24576; wg1bf[j] = f2bf(wg1[j]);
  } else if (id < 43008) {
    int j = id - 36864; int o = j / 96, k = j % 96, kt = k >> 5, ci = k & 31;
    wtcB[o * 104 + k] = f2bf(wtc[(o * 32 + ci) * 3 + kt]);
  } else if (id < 61440) {
    int j = id - 43008; int r = j / 96, c = j % 96, m = r >> 6, o = r & 63;
    const float* w = (m == 0) ? wq : (m == 1) ? wk : wv;
    wqkvB[r * 104 + c] = f2bf(w[o * 96 + c]);
  } else if (id < 65536) {
    int j = id - 61440;
    woB[(j >> 6) * 72 + (j & 63)] = f2bf(wo[j]);
  }
}

// K0b: A0..A3 -> bf16 (verified round 2)
__global__ __launch_bounds__(256) void k_prep_a(
    const float* __restrict__ A0, const float* __restrict__ A1,
    const float* __restrict__ A2, const float* __restrict__ A3,
    unsigned short* __restrict__ Abf)
{
  int idx = blockIdx.x * 256 + threadIdx.x;
  int base = idx * 4;
  if (base >= 4 * 1024 * 1024) return;
  int g = base >> 20; int r = base & 1048575;
  const float* Ag = (g == 0) ? A0 : (g == 1) ? A1 : (g == 2) ? A2 : A3;
  float4 v = *reinterpret_cast<const float4*>(Ag + r);
  ushort4 o;
  o.x = f2bf(v.x); o.y = f2bf(v.y); o.z = f2bf(v.z); o.w = f2bf(v.w);
  *reinterpret_cast<ushort4*>(Abf + base) = o;
}

// ---------------------------------------------------------------------------
// K0c (new): tem -> temT[bl][pos][32] bf16, coalesced both sides via LDS tile.
// Block = (nb 0..63 covering 16 n, bl).
__global__ __launch_bounds__(256) void k_ttr(
    const float* __restrict__ tem, unsigned short* __restrict__ temT, int b0)
{
  __shared__ __align__(16) unsigned short T[320 * 40];   // [nl*20+(t-4)][cj], pad 40
  const int nb = blockIdx.x, bl = blockIdx.y, b = b0 + bl;
  const int tid = threadIdx.x;
  for (int i = tid; i < 2560; i += 256) {        // 32cj x 16nl x 5 float4
    int cj = i / 80, r = i % 80, nl = r / 5, q = r % 5;
    float4 v = *reinterpret_cast<const float4*>(
        tem + ((size_t)(b * 32 + cj) * 1024 + nb * 16 + nl) * 24 + 4 + q * 4);
    int row = nl * 20 + q * 4;
    T[(row + 0) * 40 + cj] = f2bf(v.x);
    T[(row + 1) * 40 + cj] = f2bf(v.y);
    T[(row + 2) * 40 + cj] = f2bf(v.z);
    T[(row + 3) * 40 + cj] = f2bf(v.w);
  }
  __syncthreads();
  for (int ch = tid; ch < 1280; ch += 256) {     // 320 rows x 4 uint4
    int row = ch >> 2, seg = ch & 3;
    *reinterpret_cast<uint4*>(temT + ((size_t)bl * 20480 + nb * 320 + row) * 32 + seg * 8) =
        *reinterpret_cast<const uint4*>(&T[row * 40 + seg * 8]);
  }
}

// ---------------------------------------------------------------------------
// K1: dilated conv as MFMA; output via LDS repack -> xc[bl][pos][64] full rows.
__global__ __launch_bounds__(256) void k_conv(
    const float* __restrict__ x,
    const unsigned short* __restrict__ wtcB, const float* __restrict__ btc,
    unsigned short* __restrict__ xc, int b0)
{
  __shared__ __align__(16) unsigned short Xs[8 * 24 * 40];
  __shared__ __align__(16) unsigned short Ws[64 * 104];
  __shared__ __align__(16) unsigned short Os[128 * 72];
  const int tid = threadIdx.x, lane = tid & 63, wid = tid >> 6;
  const int wr = wid >> 1, wc = wid & 1;
  const int ptile = blockIdx.x, bl = blockIdx.y, b = b0 + bl;
  const int p0 = ptile * 128, n0 = p0 / 20;

  for (int i = tid; i < 832; i += 256) {
    int row = i / 13, seg = i % 13;
    *reinterpret_cast<uint4*>(&Ws[row * 104 + seg * 8]) =
        *reinterpret_cast<const uint4*>(wtcB + row * 104 + seg * 8);
  }
  for (int i = tid; i < 6144; i += 256) {
    int ci = i / 192, e = i % 192, nl = e / 24, t = e - nl * 24;
    int n = n0 + nl;
    float val = (n < 1024) ? x[((size_t)(b * 32 + ci) * 1024 + n) * 24 + t] : 0.f;
    Xs[(nl * 24 + t) * 40 + ci] = f2bf(val);
  }
  __syncthreads();

  int abase[4];
#pragma unroll
  for (int mi = 0; mi < 4; ++mi) {
    int r = wr * 64 + mi * 16 + (lane & 15);
    int p = p0 + r, n = p / 20, t = p - n * 20;
    abase[mi] = ((n - n0) * 24 + t) * 40 + (lane >> 4) * 8;
  }

  f32x4 acc[4][2];
#pragma unroll
  for (int mi = 0; mi < 4; ++mi)
#pragma unroll
    for (int ni = 0; ni < 2; ++ni) acc[mi][ni] = f32x4{0.f, 0.f, 0.f, 0.f};

#pragma unroll
  for (int kk = 0; kk < 3; ++kk) {
    bf16x8 a[4], bw[2];
#pragma unroll
    for (int mi = 0; mi < 4; ++mi)
      a[mi] = *reinterpret_cast<const bf16x8*>(&Xs[abase[mi] + kk * 80]);
#pragma unroll
    for (int ni = 0; ni < 2; ++ni)
      bw[ni] = *reinterpret_cast<const bf16x8*>(
          &Ws[(wc * 32 + ni * 16 + (lane & 15)) * 104 + kk * 32 + (lane >> 4) * 8]);
#pragma unroll
    for (int mi = 0; mi < 4; ++mi)
#pragma unroll
      for (int ni = 0; ni < 2; ++ni)
        acc[mi][ni] = __builtin_amdgcn_mfma_f32_16x16x32_bf16(a[mi], bw[ni], acc[mi][ni], 0, 0, 0);
  }

#pragma unroll
  for (int ni = 0; ni < 2; ++ni) {
    int col = wc * 32 + ni * 16 + (lane & 15);
    float bias = btc[col];
#pragma unroll
    for (int mi = 0; mi < 4; ++mi)
#pragma unroll
      for (int rr = 0; rr < 4; ++rr) {
        int row = wr * 64 + mi * 16 + (lane >> 4) * 4 + rr;
        Os[row * 72 + col] = f2bf(fmaxf(acc[mi][ni][rr] + bias, 0.f));
      }
  }
  __syncthreads();
  for (int ch = tid; ch < 1024; ch += 256) {     // full 128B rows, coalesced
    int row = ch >> 3, seg = ch & 7;
    *reinterpret_cast<uint4*>(xc + ((size_t)bl * 20480 + p0 + row) * 64 + seg * 8) =
        *reinterpret_cast<const uint4*>(&Os[row * 72 + seg * 8]);
  }
}

// ---------------------------------------------------------------------------
// K2: q,k,v projections. A from xc|temT; C via 2-pass LDS repack (192B half-rows).
__global__ __launch_bounds__(256) void k_qkv(
    const unsigned short* __restrict__ xc, const unsigned short* __restrict__ temT,
    const unsigned short* __restrict__ wqkvB,
    const float* __restrict__ bq, const float* __restrict__ bk,
    const float* __restrict__ bv, unsigned short* __restrict__ qkv)
{
  __shared__ __align__(16) unsigned short As[128 * 104];
  __shared__ __align__(16) unsigned short Ws[192 * 104];
  const int tid = threadIdx.x, lane = tid & 63, wid = tid >> 6;
  const int wr = wid >> 1, wc = wid & 1;
  const int ptile = blockIdx.x, bl = blockIdx.y;
  const int p0 = ptile * 128;

  for (int i = tid; i < 1536; i += 256) {
    int row = i / 12, seg = i % 12;
    uint4 v;
    if (seg < 8)
      v = *reinterpret_cast<const uint4*>(xc + ((size_t)bl * 20480 + p0 + row) * 64 + seg * 8);
    else
      v = *reinterpret_cast<const uint4*>(temT + ((size_t)bl * 20480 + p0 + row) * 32 + (seg - 8) * 8);
    *reinterpret_cast<uint4*>(&As[row * 104 + seg * 8]) = v;
  }
  for (int i = tid; i < 2496; i += 256) {
    int row = i / 13, seg = i % 13;
    *reinterpret_cast<uint4*>(&Ws[row * 104 + seg * 8]) =
        *reinterpret_cast<const uint4*>(wqkvB + row * 104 + seg * 8);
  }
  __syncthreads();

  f32x4 acc[4][6];
#pragma unroll
  for (int mi = 0; mi < 4; ++mi)
#pragma unroll
    for (int ni = 0; ni < 6; ++ni) acc[mi][ni] = f32x4{0.f, 0.f, 0.f, 0.f};

#pragma unroll
  for (int kk = 0; kk < 3; ++kk) {
    bf16x8 a[4];
#pragma unroll
    for (int mi = 0; mi < 4; ++mi)
      a[mi] = *reinterpret_cast<const bf16x8*>(
          &As[(wr * 64 + mi * 16 + (lane & 15)) * 104 + kk * 32 + (lane >> 4) * 8]);
#pragma unroll
    for (int ni = 0; ni < 6; ++ni) {
      bf16x8 bw = *reinterpret_cast<const bf16x8*>(
          &Ws[(wc * 96 + ni * 16 + (lane & 15)) * 104 + kk * 32 + (lane >> 4) * 8]);
#pragma unroll
      for (int mi = 0; mi < 4; ++mi)
        acc[mi][ni] = __builtin_amdgcn_mfma_f32_16x16x32_bf16(a[mi], bw, acc[mi][ni], 0, 0, 0);
    }
  }

  // two repack passes: pass p covers cols p*96..p*96+95 (owned by waves wc==p)
  for (int p = 0; p < 2; ++p) {
    __syncthreads();
    if (wc == p) {
#pragma unroll
      for (int ni = 0; ni < 6; ++ni) {
        int c = wc * 96 + ni * 16 + (lane & 15);
        int m = c >> 6, chn = c & 63;
        float bias = (m == 0) ? bq[chn] : (m == 1) ? bk[chn] : bv[chn];
        int colp = ni * 16 + (lane & 15);
#pragma unroll
        for (int mi = 0; mi < 4; ++mi)
#pragma unroll
          for (int rr = 0; rr < 4; ++rr) {
            int row = wr * 64 + mi * 16 + (lane >> 4) * 4 + rr;
            As[row * 104 + colp] = f2bf(acc[mi][ni][rr] + bias);
          }
      }
    }
    __syncthreads();
    for (int ch = tid; ch < 1536; ch += 256) {
      int row = ch / 12, seg = ch % 12;
      *reinterpret_cast<uint4*>(qkv + ((size_t)bl * 20480 + p0 + row) * 192 + p * 96 + seg * 8) =
          *reinterpret_cast<const uint4*>(&As[row * 104 + seg * 8]);
    }
  }
}

// ---------------------------------------------------------------------------
// K3: causal attention (verified round 5; layout unchanged)
__global__ __launch_bounds__(256) void k_att(
    const unsigned short* __restrict__ qkv, unsigned short* __restrict__ attout)
{
  const int bx = blockIdx.x;
  const int bl = bx >> 7, nb = bx & 127;
  const int tid = threadIdx.x;
  const int h = tid & 7, nl = (tid >> 3) & 7, tq = tid >> 6;
  const int n = nb * 8 + nl;
  const unsigned short* base = qkv + ((size_t)bl * 20480 + (size_t)n * 20) * 192;
  unsigned short* obase = attout + ((size_t)bl * 20480 + (size_t)n * 20) * 64;
  const float scale = 0.3535533905932738f;

  for (int j = 0; j < 5; ++j) {
    const int t = tq + 4 * j;
    union { uint4 u; unsigned short s[8]; } qr, kr, vr, orr;
    qr.u = *reinterpret_cast<const uint4*>(base + t * 192 + h * 8);
    float q[8];
#pragma unroll
    for (int d = 0; d < 8; ++d) q[d] = bf2f(qr.s[d]) * scale;
    float m = -1e30f, l = 0.f, o[8];
#pragma unroll
    for (int d = 0; d < 8; ++d) o[d] = 0.f;
    for (int s = 0; s <= t; ++s) {
      kr.u = *reinterpret_cast<const uint4*>(base + s * 192 + 64 + h * 8);
      float sc = 0.f;
#pragma unroll
      for (int d = 0; d < 8; ++d) sc += q[d] * bf2f(kr.s[d]);
      float nm = fmaxf(m, sc);
      float w = __expf(m - nm), p = __expf(sc - nm);
      vr.u = *reinterpret_cast<const uint4*>(base + s * 192 + 128 + h * 8);
      l = l * w + p;
#pragma unroll
      for (int d = 0; d < 8; ++d) o[d] = o[d] * w + p * bf2f(vr.s[d]);
      m = nm;
    }
    float inv = 1.f / l;
#pragma unroll
    for (int d = 0; d < 8; ++d) orr.s[d] = f2bf(o[d] * inv);
    *reinterpret_cast<uint4*>(obase + t * 64 + h * 8) = orr.u;
  }
}

// ---------------------------------------------------------------------------
// K4: wo GEMM; C via LDS repack (reuse As) -> x2 full rows.
__global__ __launch_bounds__(256) void k_wo(
    const unsigned short* __restrict__ attout, const unsigned short* __restrict__ woB,
    const float* __restrict__ bo, unsigned short* __restrict__ x2bf)
{
  __shared__ __align__(16) unsigned short As[128 * 72];
  __shared__ __align__(16) unsigned short Ws[64 * 72];
  const int tid = threadIdx.x, lane = tid & 63, wid = tid >> 6;
  const int wr = wid >> 1, wc = wid & 1;
  const int ptile = blockIdx.x, bl = blockIdx.y;
  const int p0 = ptile * 128;

  for (int i = tid; i < 1024; i += 256) {
    int row = i >> 3, seg = i & 7;
    *reinterpret_cast<uint4*>(&As[row * 72 + seg * 8]) =
        *reinterpret_cast<const uint4*>(attout + ((size_t)bl * 20480 + p0 + row) * 64 + seg * 8);
  }
  for (int i = tid; i < 576; i += 256) {
    int row = i / 9, seg = i % 9;
    *reinterpret_cast<uint4*>(&Ws[row * 72 + seg * 8]) =
        *reinterpret_cast<const uint4*>(woB + row * 72 + seg * 8);
  }
  __syncthreads();

  f32x4 acc[4][2];
#pragma unroll
  for (int mi = 0; mi < 4; ++mi)
#pragma unroll
    for (int ni = 0; ni < 2; ++ni) acc[mi][ni] = f32x4{0.f, 0.f, 0.f, 0.f};

#pragma unroll
  for (int kk = 0; kk < 2; ++kk) {
    bf16x8 a[4], bw[2];
#pragma unroll
    for (int mi = 0; mi < 4; ++mi)
      a[mi] = *reinterpret_cast<const bf16x8*>(
          &As[(wr * 64 + mi * 16 + (lane & 15)) * 72 + kk * 32 + (lane >> 4) * 8]);
#pragma unroll
    for (int ni = 0; ni < 2; ++ni)
      bw[ni] = *reinterpret_cast<const bf16x8*>(
          &Ws[(wc * 32 + ni * 16 + (lane & 15)) * 72 + kk * 32 + (lane >> 4) * 8]);
#pragma unroll
    for (int mi = 0; mi < 4; ++mi)
#pragma unroll
      for (int ni = 0; ni < 2; ++ni)
        acc[mi][ni] = __builtin_amdgcn_mfma_f32_16x16x32_bf16(a[mi], bw[ni], acc[mi][ni], 0, 0, 0);
  }

  __syncthreads();   // all waves done reading As
#pragma unroll
  for (int ni = 0; ni < 2; ++ni) {
    int col = wc * 32 + ni * 16 + (lane & 15);
    float bias = bo[col];
#pragma unroll
    for (int mi = 0; mi < 4; ++mi)
#pragma unroll
      for (int rr = 0; rr < 4; ++rr) {
        int row = wr * 64 + mi * 16 + (lane >> 4) * 4 + rr;
        As[row * 72 + col] = f2bf(fmaxf(acc[mi][ni][rr] + bias, 0.f));
      }
  }
  __syncthreads();
  for (int ch = tid; ch < 1024; ch += 256) {
    int row = ch >> 3, seg = ch & 7;
    int p = p0 + row, n = p / 20, t = p - n * 20;
    *reinterpret_cast<uint4*>(x2bf + ((size_t)(bl * 20 + t) * 1024 + n) * 64 + seg * 8) =
        *reinterpret_cast<const uint4*>(&As[row * 72 + seg * 8]);
  }
}

// ---------------------------------------------------------------------------
// K5: transpose x2 [btl][n][64] -> x2T [btl][64][n] (verified round 2)
__global__ __launch_bounds__(256) void k_trx2(
    const unsigned short* __restrict__ x2bf, unsigned short* __restrict__ x2t)
{
  __shared__ __align__(16) unsigned short tile[64 * 72];
  const int nb = blockIdx.x, bt = blockIdx.y;
  const int tid = threadIdx.x;
  for (int ch = tid; ch < 512; ch += 256) {
    int row = ch >> 3, seg = ch & 7;
    *reinterpret_cast<uint4*>(&tile[row * 72 + seg * 8]) =
        *reinterpret_cast<const uint4*>(x2bf + ((size_t)bt * 1024 + nb * 64 + row) * 64 + seg * 8);
  }
  __syncthreads();
  for (int ch = tid; ch < 512; ch += 256) {
    int c = ch >> 3, seg = ch & 7;
    union { unsigned short v[8]; uint4 u; } pk;
#pragma unroll
    for (int j = 0; j < 8; ++j) pk.v[j] = tile[(seg * 8 + j) * 72 + c];
    *reinterpret_cast<uint4*>(x2t + ((size_t)bt * 64 + c) * 1024 + nb * 64 + seg * 8) = pk.u;
  }
}

// ---------------------------------------------------------------------------
// K6: graph diffusion MFMA; C via LDS repack (reuse As).
__global__ __launch_bounds__(256) void k_nconv(
    const unsigned short* __restrict__ Abf,
    const unsigned short* __restrict__ x2t,
    unsigned short* __restrict__ ybf, int NT)
{
  __shared__ __align__(16) unsigned short As[128 * 72];
  __shared__ __align__(16) unsigned short Xs[64 * 72];
  const int wt = blockIdx.x & 7;
  const int btl = blockIdx.x >> 3;
  const int gl = blockIdx.y;
  const int tid = threadIdx.x, lane = tid & 63, wid = tid >> 6;
  const int wr = wid >> 1, wc = wid & 1;
  const unsigned short* Ag = Abf + (size_t)gl * 1024 * 1024 + (size_t)wt * 128 * 1024;
  const unsigned short* Xg = x2t + (size_t)btl * 64 * 1024;

  f32x4 acc[4][2];
#pragma unroll
  for (int mi = 0; mi < 4; ++mi)
#pragma unroll
    for (int ni = 0; ni < 2; ++ni) acc[mi][ni] = f32x4{0.f, 0.f, 0.f, 0.f};

  for (int vb = 0; vb < 1024; vb += 64) {
    __syncthreads();
    for (int ch = tid; ch < 1024; ch += 256) {
      int row = ch >> 3, seg = ch & 7;
      *reinterpret_cast<uint4*>(&As[row * 72 + seg * 8]) =
          *reinterpret_cast<const uint4*>(Ag + (size_t)row * 1024 + vb + seg * 8);
    }
    for (int ch = tid; ch < 512; ch += 256) {
      int row = ch >> 3, seg = ch & 7;
      *reinterpret_cast<uint4*>(&Xs[row * 72 + seg * 8]) =
          *reinterpret_cast<const uint4*>(Xg + (size_t)row * 1024 + vb + seg * 8);
    }
    __syncthreads();
#pragma unroll
    for (int kk = 0; kk < 2; ++kk) {
      bf16x8 a[4], bfr[2];
#pragma unroll
      for (int mi = 0; mi < 4; ++mi)
        a[mi] = *reinterpret_cast<const bf16x8*>(
            &As[(wr * 64 + mi * 16 + (lane & 15)) * 72 + kk * 32 + (lane >> 4) * 8]);
#pragma unroll
      for (int ni = 0; ni < 2; ++ni)
        bfr[ni] = *reinterpret_cast<const bf16x8*>(
            &Xs[(wc * 32 + ni * 16 + (lane & 15)) * 72 + kk * 32 + (lane >> 4) * 8]);
#pragma unroll
      for (int mi = 0; mi < 4; ++mi)
#pragma unroll
        for (int ni = 0; ni < 2; ++ni)
          acc[mi][ni] = __builtin_amdgcn_mfma_f32_16x16x32_bf16(a[mi], bfr[ni], acc[mi][ni], 0, 0, 0);
    }
  }

  __syncthreads();
#pragma unroll
  for (int mi = 0; mi < 4; ++mi)
#pragma unroll
    for (int ni = 0; ni < 2; ++ni)
#pragma unroll
      for (int rr = 0; rr < 4; ++rr) {
        int row = wr * 64 + mi * 16 + (lane >> 4) * 4 + rr;
        int col = wc * 32 + ni * 16 + (lane & 15);
        As[row * 72 + col] = f2bf(acc[mi][ni][rr]);
      }
  __syncthreads();
  const size_t ybase = ((size_t)(gl * NT + btl) * 1024 + wt * 128) * 64;
  for (int ch = tid; ch < 1024; ch += 256) {
    int row = ch >> 3, seg = ch & 7;
    *reinterpret_cast<uint4*>(ybf + ybase + (size_t)row * 64 + seg * 8) =
        *reinterpret_cast<const uint4*>(&As[row * 72 + seg * 8]);
  }
}

// ---------------------------------------------------------------------------
// K7: h = relu(Wg . [x2 | y0 | y1] + bg); C via LDS repack (reuse As).
__global__ __launch_bounds__(256) void k_wg(
    const unsigned short* __restrict__ x2bf,
    const unsigned short* __restrict__ ybf,
    const unsigned short* __restrict__ wgbf,
    const float* __restrict__ bg,
    unsigned short* __restrict__ hout, int NT)
{
  __shared__ __align__(16) unsigned short As[128 * 72];
  __shared__ __align__(16) unsigned short Ws[64 * 200];
  const int pt = blockIdx.x & 7;
  const int btl = blockIdx.x >> 3;
  const int tid = threadIdx.x, lane = tid & 63, wid = tid >> 6;
  const int wr = wid >> 1, wc = wid & 1;

  for (int ch = tid; ch < 1536; ch += 256) {
    int row = ch / 24, seg = ch % 24;
    *reinterpret_cast<uint4*>(&Ws[row * 200 + seg * 8]) =
        *reinterpret_cast<const uint4*>(wgbf + row * 192 + seg * 8);
  }

  f32x4 acc[4][2];
#pragma unroll
  for (int mi = 0; mi < 4; ++mi)
#pragma unroll
    for (int ni = 0; ni < 2; ++ni) acc[mi][ni] = f32x4{0.f, 0.f, 0.f, 0.f};

  for (int ks = 0; ks < 3; ++ks) {
    const unsigned short* src = (ks == 0)
        ? x2bf + ((size_t)btl * 1024 + pt * 128) * 64
        : ybf + (((size_t)((ks - 1) * NT + btl)) * 1024 + pt * 128) * 64;
    __syncthreads();
    for (int ch = tid; ch < 1024; ch += 256) {
      int row = ch >> 3, seg = ch & 7;
      *reinterpret_cast<uint4*>(&As[row * 72 + seg * 8]) =
          *reinterpret_cast<const uint4*>(src + (size_t)row * 64 + seg * 8);
    }
    __syncthreads();
#pragma unroll
    for (int kk = 0; kk < 2; ++kk) {
      bf16x8 a[4], bfr[2];
#pragma unroll
      for (int mi = 0; mi < 4; ++mi)
        a[mi] = *reinterpret_cast<const bf16x8*>(
            &As[(wr * 64 + mi * 16 + (lane & 15)) * 72 + kk * 32 + (lane >> 4) * 8]);
#pragma unroll
      for (int ni = 0; ni < 2; ++ni)
        bfr[ni] = *reinterpret_cast<const bf16x8*>(
            &Ws[(wc * 32 + ni * 16 + (lane & 15)) * 200 + ks * 64 + kk * 32 + (lane >> 4) * 8]);
#pragma unroll
      for (int mi = 0; mi < 4; ++mi)
#pragma unroll
        for (int ni = 0; ni < 2; ++ni)
          acc[mi][ni] = __builtin_amdgcn_mfma_f32_16x16x32_bf16(a[mi], bfr[ni], acc[mi][ni], 0, 0, 0);
    }
  }

  __syncthreads();
#pragma unroll
  for (int mi = 0; mi < 4; ++mi)
#pragma unroll
    for (int ni = 0; ni < 2; ++ni)
#pragma unroll
      for (int rr = 0; rr < 4; ++rr) {
        int row = wr * 64 + mi * 16 + (lane >> 4) * 4 + rr;
        int col = wc * 32 + ni * 16 + (lane & 15);
        As[row * 72 + col] = f2bf(fmaxf(acc[mi][ni][rr] + bg[col], 0.f));
      }
  __syncthreads();
  const size_t hbase = ((size_t)btl * 1024 + pt * 128) * 64;
  for (int ch = tid; ch < 1024; ch += 256) {
    int row = ch >> 3, seg = ch & 7;
    *reinterpret_cast<uint4*>(hout + hbase + (size_t)row * 64 + seg * 8) =
        *reinterpret_cast<const uint4*>(&As[row * 72 + seg * 8]);
  }
}

// ---------------------------------------------------------------------------
// K8: micro-fusion via MFMA (verified round 7; stores are full 64B sectors)
__global__ __launch_bounds__(256) void k_fuse2(
    const unsigned short* __restrict__ h0, const unsigned short* __restrict__ h1,
    const unsigned short* __restrict__ wadpB, const unsigned short* __restrict__ w0fB,
    const float* __restrict__ badp, float* __restrict__ otmp)
{
  __shared__ __align__(16) unsigned short As[128 * 136];
  __shared__ __align__(16) unsigned short Bs[64 * 136];
  __shared__ __align__(16) unsigned short Cs[64 * 72];
  const int ntile = blockIdx.x, btl = blockIdx.y;
  const int n0 = ntile * 128;
  const int tid = threadIdx.x, lane = tid & 63, wid = tid >> 6;

  for (int ch = tid; ch < 2048; ch += 256) {
    int half = ch >> 10, r = (ch >> 3) & 127, seg = ch & 7;
    const unsigned short* src = half ? h1 : h0;
    *reinterpret_cast<uint4*>(&As[r * 136 + half * 64 + seg * 8]) =
        *reinterpret_cast<const uint4*>(src + ((size_t)btl * 1024 + n0 + r) * 64 + seg * 8);
  }
  for (int ch = tid; ch < 1024; ch += 256) {
    int r = ch >> 4, seg = ch & 15;
    *reinterpret_cast<uint4*>(&Bs[r * 136 + seg * 8]) =
        *reinterpret_cast<const uint4*>(wadpB + r * 128 + seg * 8);
  }
  for (int ch = tid; ch < 512; ch += 256) {
    int r = ch >> 3, seg = ch & 7;
    *reinterpret_cast<uint4*>(&Cs[r * 72 + seg * 8]) =
        *reinterpret_cast<const uint4*>(w0fB + r * 64 + seg * 8);
  }
  __syncthreads();

  f32x4 aU[2][4], aF0[2][4], aF1[2][4];
#pragma unroll
  for (int mi = 0; mi < 2; ++mi)
#pragma unroll
    for (int ni = 0; ni < 4; ++ni) {
      aU[mi][ni] = f32x4{0.f, 0.f, 0.f, 0.f};
      aF0[mi][ni] = f32x4{0.f, 0.f, 0.f, 0.f};
      aF1[mi][ni] = f32x4{0.f, 0.f, 0.f, 0.f};
    }

  bf16x8 a[2][4];
#pragma unroll
  for (int mi = 0; mi < 2; ++mi)
#pragma unroll
    for (int kk = 0; kk < 4; ++kk)
      a[mi][kk] = *reinterpret_cast<const bf16x8*>(
          &As[(wid * 32 + mi * 16 + (lane & 15)) * 136 + kk * 32 + (lane >> 4) * 8]);

#pragma unroll
  for (int kk = 0; kk < 4; ++kk)
#pragma unroll
    for (int ni = 0; ni < 4; ++ni) {
      bf16x8 bw = *reinterpret_cast<const bf16x8*>(
          &Bs[(ni * 16 + (lane & 15)) * 136 + kk * 32 + (lane >> 4) * 8]);
#pragma unroll
      for (int mi = 0; mi < 2; ++mi)
        aU[mi][ni] = __builtin_amdgcn_mfma_f32_16x16x32_bf16(a[mi][kk], bw, aU[mi][ni], 0, 0, 0);
    }
#pragma unroll
  for (int kk = 0; kk < 2; ++kk)
#pragma unroll
    for (int ni = 0; ni < 4; ++ni) {
      bf16x8 cw = *reinterpret_cast<const bf16x8*>(
          &Cs[(ni * 16 + (lane & 15)) * 72 + kk * 32 + (lane >> 4) * 8]);
#pragma unroll
      for (int mi = 0; mi < 2; ++mi) {
        aF0[mi][ni] = __builtin_amdgcn_mfma_f32_16x16x32_bf16(a[mi][kk], cw, aF0[mi][ni], 0, 0, 0);
        aF1[mi][ni] = __builtin_amdgcn_mfma_f32_16x16x32_bf16(a[mi][kk + 2], cw, aF1[mi][ni], 0, 0, 0);
      }
    }

  float bcol[4];
#pragma unroll
  for (int ni = 0; ni < 4; ++ni) bcol[ni] = badp[ni * 16 + (lane & 15)];

#pragma unroll
  for (int mi = 0; mi < 2; ++mi)
#pragma unroll
    for (int rr = 0; rr < 4; ++rr) {
      float s0 = 0.f, s1 = 0.f;
#pragma unroll
      for (int ni = 0; ni < 4; ++ni) {
        float u = aU[mi][ni][rr] + bcol[ni];
        s0 += aF0[mi][ni][rr] * u;
        s1 += aF1[mi][ni][rr] * u;
      }
#pragma unroll
      for (int off = 1; off < 16; off <<= 1) {
        s0 += __shfl_xor(s0, off);
        s1 += __shfl_xor(s1, off);
      }
      float mmax = fmaxf(s0, s1);
      float e0 = __expf(s0 - mmax), e1 = __expf(s1 - mmax);
      float a0w = e0 / (e0 + e1);
      int row = wid * 32 + mi * 16 + (lane >> 4) * 4 + rr;
      size_t base = ((size_t)btl * 1024 + n0 + row) * 64;
#pragma unroll
      for (int ni = 0; ni < 4; ++ni)
        otmp[base + ni * 16 + (lane & 15)] =
            a0w * aF0[mi][ni][rr] + (1.f - a0w) * aF1[mi][ni][rr];
    }
}

// ---------------------------------------------------------------------------
// K9: otmp -> out [b][c][n][t] (verified round 7)
__global__ __launch_bounds__(256) void k_otr(
    const float* __restrict__ otmp, float* __restrict__ out, int b0)
{
  __shared__ __align__(16) float tile[160 * 68];
  const int nb = blockIdx.x;
  const int bl = blockIdx.y;
  const int b = b0 + bl;
  const int tid = threadIdx.x;

  for (int ch = tid; ch < 2560; ch += 256) {
    int t = ch >> 7, rem = ch & 127, nl = rem >> 4, seg = rem & 15;
    *reinterpret_cast<float4*>(&tile[(nl * 20 + t) * 68 + seg * 4]) =
        *reinterpret_cast<const float4*>(
            otmp + ((size_t)(bl * 20 + t) * 1024 + nb * 8 + nl) * 64 + seg * 4);
  }
  __syncthreads();
  for (int ch = tid; ch < 2560; ch += 256) {
    int tq = ch % 5, pair = ch / 5;
    int nl = pair & 7, cc = pair >> 3;
    float4 v;
    v.x = tile[(nl * 20 + tq * 4 + 0) * 68 + cc];
    v.y = tile[(nl * 20 + tq * 4 + 1) * 68 + cc];
    v.z = tile[(nl * 20 + tq * 4 + 2) * 68 + cc];
    v.w = tile[(nl * 20 + tq * 4 + 3) * 68 + cc];
    *reinterpret_cast<float4*>(
        out + ((size_t)(b * 64 + cc) * 1024 + nb * 8 + nl) * 20 + tq * 4) = v;
  }
}

// ---------------------------------------------------------------------------
extern "C" void kernel_launch(void* const* d_in, const int* in_sizes, int n_in,
                              void* d_out, int out_size, void* d_ws, size_t ws_size,
                              hipStream_t stream) {
  (void)in_sizes; (void)n_in; (void)out_size;
  const float* x    = (const float*)d_in[0];
  const float* tem  = (const float*)d_in[1];
  const float* A0   = (const float*)d_in[2];
  const float* A1   = (const float*)d_in[3];
  const float* A2   = (const float*)d_in[4];
  const float* A3   = (const float*)d_in[5];
  const float* wtc  = (const float*)d_in[6];
  const float* btc  = (const float*)d_in[7];
  const float* wq   = (const float*)d_in[8];
  const float* bq   = (const float*)d_in[9];
  const float* wk   = (const float*)d_in[10];
  const float* bk   = (const float*)d_in[11];
  const float* wv   = (const float*)d_in[12];
  const float* bv   = (const float*)d_in[13];
  const float* wo   = (const float*)d_in[14];
  const float* bo   = (const float*)d_in[15];
  const float* wg0  = (const float*)d_in[16];
  const float* bg0  = (const float*)d_in[17];
  const float* wg1  = (const float*)d_in[18];
  const float* bg1  = (const float*)d_in[19];
  const float* wadp = (const float*)d_in[20];
  const float* badp = (const float*)d_in[21];
  const float* w0f  = (const float*)d_in[22];

  char* ws = (char*)d_ws;
  unsigned short* wadpB = (unsigned short*)(ws + WADPB_OFF);
  unsigned short* w0fB  = (unsigned short*)(ws + W0FB_OFF);
  unsigned short* wg0bf = (unsigned short*)(ws + WG0_OFF);
  unsigned short* wg1bf = (unsigned short*)(ws + WG1_OFF);
  unsigned short* wtcB  = (unsigned short*)(ws + WTCB_OFF);
  unsigned short* wqkvB = (unsigned short*)(ws + WQKVB_OFF);
  unsigned short* woB   = (unsigned short*)(ws + WOB_OFF);
  unsigned short* Abf   = (unsigned short*)(ws + ABF_OFF);

  // per-b slab sizes (bytes)
  const size_t SBH  = (size_t)20480 * 64 * 2;    // 2.62 MB  (xc / attout / x2 / h0)
  const size_t SBT  = (size_t)20480 * 32 * 2;    // 1.31 MB  (temT)
  const size_t SBQ  = (size_t)20480 * 192 * 2;   // 7.86 MB  (qkv; x2+x2T overlay)
  const size_t SBY  = 2 * SBH;                   // 5.24 MB  (y pair / otmp fp32)
  int CB = 1;
  {
    const int cands[4] = {16, 8, 4, 2};
    for (int i = 0; i < 4; ++i) {
      size_t need = CHUNK0 + (size_t)cands[i] * (SBH + SBT + SBQ + SBY + SBH);
      if (need <= ws_size) { CB = cands[i]; break; }
    }
  }
  const int NT = CB * TO;
  const size_t XC0  = CHUNK0;
  const size_t TT0  = XC0 + (size_t)CB * SBH;
  const size_t QKV0 = TT0 + (size_t)CB * SBT;
  const size_t Y0   = QKV0 + (size_t)CB * SBQ;
  const size_t H00  = Y0 + (size_t)CB * SBY;
  unsigned short* xc     = (unsigned short*)(ws + XC0);
  unsigned short* temT   = (unsigned short*)(ws + TT0);
  unsigned short* qkvbuf = (unsigned short*)(ws + QKV0);
  unsigned short* attout = (unsigned short*)(ws + XC0);            // overlay xc (dead)
  unsigned short* x2bf   = (unsigned short*)(ws + QKV0);           // overlay qkv (dead)
  unsigned short* x2t    = (unsigned short*)(ws + QKV0 + (size_t)CB * SBH);
  unsigned short* ybuf   = (unsigned short*)(ws + Y0);
  unsigned short* h0     = (unsigned short*)(ws + H00);
  unsigned short* h1     = x2t;                                    // overlay x2t (dead)
  float* otmp            = (float*)(ws + Y0);                      // overlay ybuf (dead)
  float* out = (float*)d_out;

  k_prep_w<<<dim3(256), dim3(256), 0, stream>>>(wtc, wq, wk, wv, wo, wadp, w0f,
                                                wg0, wg1, wadpB, w0fB, wg0bf, wg1bf,
                                                wtcB, wqkvB, woB);
  k_prep_a<<<dim3(4096), dim3(256), 0, stream>>>(A0, A1, A2, A3, Abf);

  for (int b0 = 0; b0 < BB; b0 += CB) {
    k_ttr<<<dim3(64, CB), dim3(256), 0, stream>>>(tem, temT, b0);
    k_conv<<<dim3(160, CB), dim3(256), 0, stream>>>(x, wtcB, btc, xc, b0);
    k_qkv<<<dim3(160, CB), dim3(256), 0, stream>>>(xc, temT, wqkvB, bq, bk, bv, qkvbuf);
    k_att<<<dim3(CB * 128), dim3(256), 0, stream>>>(qkvbuf, attout);
    k_wo<<<dim3(160, CB), dim3(256), 0, stream>>>(attout, woB, bo, x2bf);
    k_trx2<<<dim3(16, NT), dim3(256), 0, stream>>>(x2bf, x2t);
    k_nconv<<<dim3(8 * NT, 2), dim3(256), 0, stream>>>(Abf, x2t, ybuf, NT);
    k_wg<<<dim3(8 * NT), dim3(256), 0, stream>>>(x2bf, ybuf, wg0bf, bg0, h0, NT);
    k_nconv<<<dim3(8 * NT, 2), dim3(256), 0, stream>>>(Abf + 2 * 1024 * 1024, x2t, ybuf, NT);
    k_wg<<<dim3(8 * NT), dim3(256), 0, stream>>>(x2bf, ybuf, wg1bf, bg1, h1, NT);
    k_fuse2<<<dim3(8, NT), dim3(256), 0, stream>>>(h0, h1, wadpB, w0fB, badp, otmp);
    k_otr<<<dim3(128, CB), dim3(256), 0, stream>>>(otmp, out, b0);
  }
}

// Round 9
// 844.802 us; speedup vs baseline: 1.7473x; 1.1758x over previous
//
#include <hip/hip_runtime.h>
#include <hip/hip_bf16.h>
#include <stdint.h>

// ---------------------------------------------------------------------------
constexpr int BB=16, CIN=32, CO=64, NNODE=1024, TT=24, KTAP=3, DTEM=32, NH=8, HD=8, TO=20;

typedef __attribute__((ext_vector_type(4))) float f32x4;
typedef __attribute__((ext_vector_type(8))) short bf16x8;

__device__ __forceinline__ unsigned short f2bf(float f) {
  union { float f; unsigned u; } v; v.f = f;
  unsigned r = v.u + 0x7FFFu + ((v.u >> 16) & 1u);
  return (unsigned short)(r >> 16);
}
__device__ __forceinline__ float bf2f(unsigned short s) {
  union { unsigned u; float f; } v; v.u = ((unsigned)s) << 16; return v.f;
}
// async global->LDS, 16B per lane; LDS dest = wave-uniform base + lane*16
__device__ __forceinline__ void gl_lds16(const unsigned short* g, unsigned short* l) {
  __builtin_amdgcn_global_load_lds(
      (const __attribute__((address_space(1))) unsigned int*)g,
      (__attribute__((address_space(3))) unsigned int*)l, 16, 0, 0);
}

// ws fixed offsets (bytes)
constexpr size_t WADPB_OFF = 0;        // bf16 [64][128]
constexpr size_t W0FB_OFF  = 16384;    // bf16 [64][64]
constexpr size_t WG0_OFF   = 163840;
constexpr size_t WG1_OFF   = 188416;
constexpr size_t WTCB_OFF  = 212992;   // bf16 [64][104]
constexpr size_t WQKVB_OFF = 226304;   // bf16 [192][104]
constexpr size_t WOB_OFF   = 266240;   // bf16 [64][72]
constexpr size_t ABF_OFF   = (size_t)1 << 20;   // bf16 [4][1024][1024]
constexpr size_t CHUNK0    = (size_t)12 << 20;

// ---------------------------------------------------------------------------
// K0a: weight prep (verified round 7)
__global__ __launch_bounds__(256) void k_prep_w(
    const float* __restrict__ wtc, const float* __restrict__ wq,
    const float* __restrict__ wk,  const float* __restrict__ wv,
    const float* __restrict__ wo,  const float* __restrict__ wadp,
    const float* __restrict__ w0f, const float* __restrict__ wg0,
    const float* __restrict__ wg1,
    unsigned short* __restrict__ wadpB, unsigned short* __restrict__ w0fB,
    unsigned short* __restrict__ wg0bf, unsigned short* __restrict__ wg1bf,
    unsigned short* __restrict__ wtcB,  unsigned short* __restrict__ wqkvB,
    unsigned short* __restrict__ woB)
{
  int id = blockIdx.x * 256 + threadIdx.x;
  if (id < 8192) {
    wadpB[id] = f2bf(wadp[id]);
  } else if (id < 12288) {
    int j = id - 8192; w0fB[j] = f2bf(w0f[j]);
  } else if (id < 24576) {
    int j = id - 12288; wg0bf[j] = f2bf(wg0[j]);
  } else if (id < 36864) {
    int j = id - 24576; wg1bf[j] = f2bf(wg1[j]);
  } else if (id < 43008) {
    int j = id - 36864; int o = j / 96, k = j % 96, kt = k >> 5, ci = k & 31;
    wtcB[o * 104 + k] = f2bf(wtc[(o * 32 + ci) * 3 + kt]);
  } else if (id < 61440) {
    int j = id - 43008; int r = j / 96, c = j % 96, m = r >> 6, o = r & 63;
    const float* w = (m == 0) ? wq : (m == 1) ? wk : wv;
    wqkvB[r * 104 + c] = f2bf(w[o * 96 + c]);
  } else if (id < 65536) {
    int j = id - 61440;
    woB[(j >> 6) * 72 + (j & 63)] = f2bf(wo[j]);
  }
}

// K0b: A0..A3 -> bf16 (verified round 2)
__global__ __launch_bounds__(256) void k_prep_a(
    const float* __restrict__ A0, const float* __restrict__ A1,
    const float* __restrict__ A2, const float* __restrict__ A3,
    unsigned short* __restrict__ Abf)
{
  int idx = blockIdx.x * 256 + threadIdx.x;
  int base = idx * 4;
  if (base >= 4 * 1024 * 1024) return;
  int g = base >> 20; int r = base & 1048575;
  const float* Ag = (g == 0) ? A0 : (g == 1) ? A1 : (g == 2) ? A2 : A3;
  float4 v = *reinterpret_cast<const float4*>(Ag + r);
  ushort4 o;
  o.x = f2bf(v.x); o.y = f2bf(v.y); o.z = f2bf(v.z); o.w = f2bf(v.w);
  *reinterpret_cast<ushort4*>(Abf + base) = o;
}

// ---------------------------------------------------------------------------
// K0c: tem -> temT[bl][pos][32] bf16 (verified round 8)
__global__ __launch_bounds__(256) void k_ttr(
    const float* __restrict__ tem, unsigned short* __restrict__ temT, int b0)
{
  __shared__ __align__(16) unsigned short T[320 * 40];
  const int nb = blockIdx.x, bl = blockIdx.y, b = b0 + bl;
  const int tid = threadIdx.x;
  for (int i = tid; i < 2560; i += 256) {
    int cj = i / 80, r = i % 80, nl = r / 5, q = r % 5;
    float4 v = *reinterpret_cast<const float4*>(
        tem + ((size_t)(b * 32 + cj) * 1024 + nb * 16 + nl) * 24 + 4 + q * 4);
    int row = nl * 20 + q * 4;
    T[(row + 0) * 40 + cj] = f2bf(v.x);
    T[(row + 1) * 40 + cj] = f2bf(v.y);
    T[(row + 2) * 40 + cj] = f2bf(v.z);
    T[(row + 3) * 40 + cj] = f2bf(v.w);
  }
  __syncthreads();
  for (int ch = tid; ch < 1280; ch += 256) {
    int row = ch >> 2, seg = ch & 3;
    *reinterpret_cast<uint4*>(temT + ((size_t)bl * 20480 + nb * 320 + row) * 32 + seg * 8) =
        *reinterpret_cast<const uint4*>(&T[row * 40 + seg * 8]);
  }
}

// ---------------------------------------------------------------------------
// K1: dilated conv as MFMA (verified round 8)
__global__ __launch_bounds__(256) void k_conv(
    const float* __restrict__ x,
    const unsigned short* __restrict__ wtcB, const float* __restrict__ btc,
    unsigned short* __restrict__ xc, int b0)
{
  __shared__ __align__(16) unsigned short Xs[8 * 24 * 40];
  __shared__ __align__(16) unsigned short Ws[64 * 104];
  __shared__ __align__(16) unsigned short Os[128 * 72];
  const int tid = threadIdx.x, lane = tid & 63, wid = tid >> 6;
  const int wr = wid >> 1, wc = wid & 1;
  const int ptile = blockIdx.x, bl = blockIdx.y, b = b0 + bl;
  const int p0 = ptile * 128, n0 = p0 / 20;

  for (int i = tid; i < 832; i += 256) {
    int row = i / 13, seg = i % 13;
    *reinterpret_cast<uint4*>(&Ws[row * 104 + seg * 8]) =
        *reinterpret_cast<const uint4*>(wtcB + row * 104 + seg * 8);
  }
  for (int i = tid; i < 6144; i += 256) {
    int ci = i / 192, e = i % 192, nl = e / 24, t = e - nl * 24;
    int n = n0 + nl;
    float val = (n < 1024) ? x[((size_t)(b * 32 + ci) * 1024 + n) * 24 + t] : 0.f;
    Xs[(nl * 24 + t) * 40 + ci] = f2bf(val);
  }
  __syncthreads();

  int abase[4];
#pragma unroll
  for (int mi = 0; mi < 4; ++mi) {
    int r = wr * 64 + mi * 16 + (lane & 15);
    int p = p0 + r, n = p / 20, t = p - n * 20;
    abase[mi] = ((n - n0) * 24 + t) * 40 + (lane >> 4) * 8;
  }

  f32x4 acc[4][2];
#pragma unroll
  for (int mi = 0; mi < 4; ++mi)
#pragma unroll
    for (int ni = 0; ni < 2; ++ni) acc[mi][ni] = f32x4{0.f, 0.f, 0.f, 0.f};

#pragma unroll
  for (int kk = 0; kk < 3; ++kk) {
    bf16x8 a[4], bw[2];
#pragma unroll
    for (int mi = 0; mi < 4; ++mi)
      a[mi] = *reinterpret_cast<const bf16x8*>(&Xs[abase[mi] + kk * 80]);
#pragma unroll
    for (int ni = 0; ni < 2; ++ni)
      bw[ni] = *reinterpret_cast<const bf16x8*>(
          &Ws[(wc * 32 + ni * 16 + (lane & 15)) * 104 + kk * 32 + (lane >> 4) * 8]);
#pragma unroll
    for (int mi = 0; mi < 4; ++mi)
#pragma unroll
      for (int ni = 0; ni < 2; ++ni)
        acc[mi][ni] = __builtin_amdgcn_mfma_f32_16x16x32_bf16(a[mi], bw[ni], acc[mi][ni], 0, 0, 0);
  }

#pragma unroll
  for (int ni = 0; ni < 2; ++ni) {
    int col = wc * 32 + ni * 16 + (lane & 15);
    float bias = btc[col];
#pragma unroll
    for (int mi = 0; mi < 4; ++mi)
#pragma unroll
      for (int rr = 0; rr < 4; ++rr) {
        int row = wr * 64 + mi * 16 + (lane >> 4) * 4 + rr;
        Os[row * 72 + col] = f2bf(fmaxf(acc[mi][ni][rr] + bias, 0.f));
      }
  }
  __syncthreads();
  for (int ch = tid; ch < 1024; ch += 256) {
    int row = ch >> 3, seg = ch & 7;
    *reinterpret_cast<uint4*>(xc + ((size_t)bl * 20480 + p0 + row) * 64 + seg * 8) =
        *reinterpret_cast<const uint4*>(&Os[row * 72 + seg * 8]);
  }
}

// ---------------------------------------------------------------------------
// K2: q,k,v projections (verified round 8)
__global__ __launch_bounds__(256) void k_qkv(
    const unsigned short* __restrict__ xc, const unsigned short* __restrict__ temT,
    const unsigned short* __restrict__ wqkvB,
    const float* __restrict__ bq, const float* __restrict__ bk,
    const float* __restrict__ bv, unsigned short* __restrict__ qkv)
{
  __shared__ __align__(16) unsigned short As[128 * 104];
  __shared__ __align__(16) unsigned short Ws[192 * 104];
  const int tid = threadIdx.x, lane = tid & 63, wid = tid >> 6;
  const int wr = wid >> 1, wc = wid & 1;
  const int ptile = blockIdx.x, bl = blockIdx.y;
  const int p0 = ptile * 128;

  for (int i = tid; i < 1536; i += 256) {
    int row = i / 12, seg = i % 12;
    uint4 v;
    if (seg < 8)
      v = *reinterpret_cast<const uint4*>(xc + ((size_t)bl * 20480 + p0 + row) * 64 + seg * 8);
    else
      v = *reinterpret_cast<const uint4*>(temT + ((size_t)bl * 20480 + p0 + row) * 32 + (seg - 8) * 8);
    *reinterpret_cast<uint4*>(&As[row * 104 + seg * 8]) = v;
  }
  for (int i = tid; i < 2496; i += 256) {
    int row = i / 13, seg = i % 13;
    *reinterpret_cast<uint4*>(&Ws[row * 104 + seg * 8]) =
        *reinterpret_cast<const uint4*>(wqkvB + row * 104 + seg * 8);
  }
  __syncthreads();

  f32x4 acc[4][6];
#pragma unroll
  for (int mi = 0; mi < 4; ++mi)
#pragma unroll
    for (int ni = 0; ni < 6; ++ni) acc[mi][ni] = f32x4{0.f, 0.f, 0.f, 0.f};

#pragma unroll
  for (int kk = 0; kk < 3; ++kk) {
    bf16x8 a[4];
#pragma unroll
    for (int mi = 0; mi < 4; ++mi)
      a[mi] = *reinterpret_cast<const bf16x8*>(
          &As[(wr * 64 + mi * 16 + (lane & 15)) * 104 + kk * 32 + (lane >> 4) * 8]);
#pragma unroll
    for (int ni = 0; ni < 6; ++ni) {
      bf16x8 bw = *reinterpret_cast<const bf16x8*>(
          &Ws[(wc * 96 + ni * 16 + (lane & 15)) * 104 + kk * 32 + (lane >> 4) * 8]);
#pragma unroll
      for (int mi = 0; mi < 4; ++mi)
        acc[mi][ni] = __builtin_amdgcn_mfma_f32_16x16x32_bf16(a[mi], bw, acc[mi][ni], 0, 0, 0);
    }
  }

  for (int p = 0; p < 2; ++p) {
    __syncthreads();
    if (wc == p) {
#pragma unroll
      for (int ni = 0; ni < 6; ++ni) {
        int c = wc * 96 + ni * 16 + (lane & 15);
        int m = c >> 6, chn = c & 63;
        float bias = (m == 0) ? bq[chn] : (m == 1) ? bk[chn] : bv[chn];
        int colp = ni * 16 + (lane & 15);
#pragma unroll
        for (int mi = 0; mi < 4; ++mi)
#pragma unroll
          for (int rr = 0; rr < 4; ++rr) {
            int row = wr * 64 + mi * 16 + (lane >> 4) * 4 + rr;
            As[row * 104 + colp] = f2bf(acc[mi][ni][rr] + bias);
          }
      }
    }
    __syncthreads();
    for (int ch = tid; ch < 1536; ch += 256) {
      int row = ch / 12, seg = ch % 12;
      *reinterpret_cast<uint4*>(qkv + ((size_t)bl * 20480 + p0 + row) * 192 + p * 96 + seg * 8) =
          *reinterpret_cast<const uint4*>(&As[row * 104 + seg * 8]);
    }
  }
}

// ---------------------------------------------------------------------------
// K3: causal attention (verified round 5)
__global__ __launch_bounds__(256) void k_att(
    const unsigned short* __restrict__ qkv, unsigned short* __restrict__ attout)
{
  const int bx = blockIdx.x;
  const int bl = bx >> 7, nb = bx & 127;
  const int tid = threadIdx.x;
  const int h = tid & 7, nl = (tid >> 3) & 7, tq = tid >> 6;
  const int n = nb * 8 + nl;
  const unsigned short* base = qkv + ((size_t)bl * 20480 + (size_t)n * 20) * 192;
  unsigned short* obase = attout + ((size_t)bl * 20480 + (size_t)n * 20) * 64;
  const float scale = 0.3535533905932738f;

  for (int j = 0; j < 5; ++j) {
    const int t = tq + 4 * j;
    union { uint4 u; unsigned short s[8]; } qr, kr, vr, orr;
    qr.u = *reinterpret_cast<const uint4*>(base + t * 192 + h * 8);
    float q[8];
#pragma unroll
    for (int d = 0; d < 8; ++d) q[d] = bf2f(qr.s[d]) * scale;
    float m = -1e30f, l = 0.f, o[8];
#pragma unroll
    for (int d = 0; d < 8; ++d) o[d] = 0.f;
    for (int s = 0; s <= t; ++s) {
      kr.u = *reinterpret_cast<const uint4*>(base + s * 192 + 64 + h * 8);
      float sc = 0.f;
#pragma unroll
      for (int d = 0; d < 8; ++d) sc += q[d] * bf2f(kr.s[d]);
      float nm = fmaxf(m, sc);
      float w = __expf(m - nm), p = __expf(sc - nm);
      vr.u = *reinterpret_cast<const uint4*>(base + s * 192 + 128 + h * 8);
      l = l * w + p;
#pragma unroll
      for (int d = 0; d < 8; ++d) o[d] = o[d] * w + p * bf2f(vr.s[d]);
      m = nm;
    }
    float inv = 1.f / l;
#pragma unroll
    for (int d = 0; d < 8; ++d) orr.s[d] = f2bf(o[d] * inv);
    *reinterpret_cast<uint4*>(obase + t * 64 + h * 8) = orr.u;
  }
}

// ---------------------------------------------------------------------------
// K4: wo GEMM (verified round 8)
__global__ __launch_bounds__(256) void k_wo(
    const unsigned short* __restrict__ attout, const unsigned short* __restrict__ woB,
    const float* __restrict__ bo, unsigned short* __restrict__ x2bf)
{
  __shared__ __align__(16) unsigned short As[128 * 72];
  __shared__ __align__(16) unsigned short Ws[64 * 72];
  const int tid = threadIdx.x, lane = tid & 63, wid = tid >> 6;
  const int wr = wid >> 1, wc = wid & 1;
  const int ptile = blockIdx.x, bl = blockIdx.y;
  const int p0 = ptile * 128;

  for (int i = tid; i < 1024; i += 256) {
    int row = i >> 3, seg = i & 7;
    *reinterpret_cast<uint4*>(&As[row * 72 + seg * 8]) =
        *reinterpret_cast<const uint4*>(attout + ((size_t)bl * 20480 + p0 + row) * 64 + seg * 8);
  }
  for (int i = tid; i < 576; i += 256) {
    int row = i / 9, seg = i % 9;
    *reinterpret_cast<uint4*>(&Ws[row * 72 + seg * 8]) =
        *reinterpret_cast<const uint4*>(woB + row * 72 + seg * 8);
  }
  __syncthreads();

  f32x4 acc[4][2];
#pragma unroll
  for (int mi = 0; mi < 4; ++mi)
#pragma unroll
    for (int ni = 0; ni < 2; ++ni) acc[mi][ni] = f32x4{0.f, 0.f, 0.f, 0.f};

#pragma unroll
  for (int kk = 0; kk < 2; ++kk) {
    bf16x8 a[4], bw[2];
#pragma unroll
    for (int mi = 0; mi < 4; ++mi)
      a[mi] = *reinterpret_cast<const bf16x8*>(
          &As[(wr * 64 + mi * 16 + (lane & 15)) * 72 + kk * 32 + (lane >> 4) * 8]);
#pragma unroll
    for (int ni = 0; ni < 2; ++ni)
      bw[ni] = *reinterpret_cast<const bf16x8*>(
          &Ws[(wc * 32 + ni * 16 + (lane & 15)) * 72 + kk * 32 + (lane >> 4) * 8]);
#pragma unroll
    for (int mi = 0; mi < 4; ++mi)
#pragma unroll
      for (int ni = 0; ni < 2; ++ni)
        acc[mi][ni] = __builtin_amdgcn_mfma_f32_16x16x32_bf16(a[mi], bw[ni], acc[mi][ni], 0, 0, 0);
  }

  __syncthreads();
#pragma unroll
  for (int ni = 0; ni < 2; ++ni) {
    int col = wc * 32 + ni * 16 + (lane & 15);
    float bias = bo[col];
#pragma unroll
    for (int mi = 0; mi < 4; ++mi)
#pragma unroll
      for (int rr = 0; rr < 4; ++rr) {
        int row = wr * 64 + mi * 16 + (lane >> 4) * 4 + rr;
        As[row * 72 + col] = f2bf(fmaxf(acc[mi][ni][rr] + bias, 0.f));
      }
  }
  __syncthreads();
  for (int ch = tid; ch < 1024; ch += 256) {
    int row = ch >> 3, seg = ch & 7;
    int p = p0 + row, n = p / 20, t = p - n * 20;
    *reinterpret_cast<uint4*>(x2bf + ((size_t)(bl * 20 + t) * 1024 + n) * 64 + seg * 8) =
        *reinterpret_cast<const uint4*>(&As[row * 72 + seg * 8]);
  }
}

// ---------------------------------------------------------------------------
// K5: transpose x2 [btl][n][64] -> x2T [btl][64][n] (verified round 2)
__global__ __launch_bounds__(256) void k_trx2(
    const unsigned short* __restrict__ x2bf, unsigned short* __restrict__ x2t)
{
  __shared__ __align__(16) unsigned short tile[64 * 72];
  const int nb = blockIdx.x, bt = blockIdx.y;
  const int tid = threadIdx.x;
  for (int ch = tid; ch < 512; ch += 256) {
    int row = ch >> 3, seg = ch & 7;
    *reinterpret_cast<uint4*>(&tile[row * 72 + seg * 8]) =
        *reinterpret_cast<const uint4*>(x2bf + ((size_t)bt * 1024 + nb * 64 + row) * 64 + seg * 8);
  }
  __syncthreads();
  for (int ch = tid; ch < 512; ch += 256) {
    int c = ch >> 3, seg = ch & 7;
    union { unsigned short v[8]; uint4 u; } pk;
#pragma unroll
    for (int j = 0; j < 8; ++j) pk.v[j] = tile[(seg * 8 + j) * 72 + c];
    *reinterpret_cast<uint4*>(x2t + ((size_t)bt * 64 + c) * 1024 + nb * 64 + seg * 8) = pk.u;
  }
}

// ---------------------------------------------------------------------------
// K6 (rewritten): graph diffusion as flat GEMM. Per graph: M=1024 (w),
// N=NT*64 (bt,c: x2t rows ARE contiguous K=1024 B-rows), K=1024.
// 128x128 tile (2x2 waves x 64x64), K-step 64, global_load_lds width 16
// with XOR-swizzled SOURCE addr (slot^(row&7)) + matching swizzled ds_read
// (both-sides rule); XCD-chunked block swizzle for B-tile L2 locality.
__global__ __launch_bounds__(256) void k_nconv(
    const unsigned short* __restrict__ Abf,
    const unsigned short* __restrict__ x2t,
    unsigned short* __restrict__ ybf, int NT)
{
  __shared__ __align__(16) unsigned short As[128 * 64];   // linear (gload_lds)
  __shared__ __align__(16) unsigned short Bs[128 * 64];
  __shared__ __align__(16) unsigned short Cs[128 * 72];   // repack scratch
  const int nwg = gridDim.x;                  // (NT/2)*8, multiple of 8
  const int chunk = nwg >> 3;
  const int bx = blockIdx.x;
  const int v = (bx & 7) * chunk + (bx >> 3); // XCD-chunked swizzle (m157)
  const int wt = v & 7;                       // A row-tile (8 blocks share ntile -> same XCD)
  const int ntile = v >> 3;                   // 128-col tile of N
  const int gl = blockIdx.y;
  const int tid = threadIdx.x, lane = tid & 63, wid = tid >> 6;
  const int wr = wid >> 1, wc = wid & 1;      // 2x2 waves, each 64x64
  const int lrow = lane >> 3, lslot = lane & 7;
  const unsigned short* Ag = Abf + (size_t)gl * 1024 * 1024 + (size_t)wt * 128 * 1024;
  const unsigned short* Bg = x2t + (size_t)ntile * 128 * 1024;

  f32x4 acc[4][4];
#pragma unroll
  for (int mi = 0; mi < 4; ++mi)
#pragma unroll
    for (int ni = 0; ni < 4; ++ni) acc[mi][ni] = f32x4{0.f, 0.f, 0.f, 0.f};

  for (int vb = 0; vb < 1024; vb += 64) {
    __syncthreads();
    // stage A,B tiles: each wave stages 32 rows of each via 4 gload_lds calls
#pragma unroll
    for (int j = 0; j < 4; ++j) {
      int r = wid * 32 + j * 8 + lrow;                 // tile-local row
      int so = (lslot ^ (r & 7)) << 3;                 // swizzled src slot (elems)
      gl_lds16(Ag + (size_t)r * 1024 + vb + so, As + (wid * 32 + j * 8) * 64);
      gl_lds16(Bg + (size_t)r * 1024 + vb + so, Bs + (wid * 32 + j * 8) * 64);
    }
    __syncthreads();   // drains vmcnt before use
#pragma unroll
    for (int kk = 0; kk < 2; ++kk) {
      const int hi = lane >> 4;
      bf16x8 a[4], bfr[4];
#pragma unroll
      for (int mi = 0; mi < 4; ++mi) {
        int row = wr * 64 + mi * 16 + (lane & 15);
        a[mi] = *reinterpret_cast<const bf16x8*>(
            &As[row * 64 + (((kk * 4 + hi) ^ (row & 7)) << 3)]);
      }
#pragma unroll
      for (int ni = 0; ni < 4; ++ni) {
        int row = wc * 64 + ni * 16 + (lane & 15);
        bfr[ni] = *reinterpret_cast<const bf16x8*>(
            &Bs[row * 64 + (((kk * 4 + hi) ^ (row & 7)) << 3)]);
      }
#pragma unroll
      for (int mi = 0; mi < 4; ++mi)
#pragma unroll
        for (int ni = 0; ni < 4; ++ni)
          acc[mi][ni] = __builtin_amdgcn_mfma_f32_16x16x32_bf16(a[mi], bfr[ni], acc[mi][ni], 0, 0, 0);
    }
  }

  // C repack + store, one 64-col half (= one btl) at a time
  for (int h = 0; h < 2; ++h) {
    __syncthreads();
    if (wc == h) {
#pragma unroll
      for (int mi = 0; mi < 4; ++mi)
#pragma unroll
        for (int ni = 0; ni < 4; ++ni)
#pragma unroll
          for (int rr = 0; rr < 4; ++rr) {
            int row = wr * 64 + mi * 16 + (lane >> 4) * 4 + rr;
            int col = ni * 16 + (lane & 15);
            Cs[row * 72 + col] = f2bf(acc[mi][ni][rr]);
          }
    }
    __syncthreads();
    const int btl = ntile * 2 + h;
    const size_t ybase = ((size_t)(gl * NT + btl) * 1024 + wt * 128) * 64;
    for (int ch = tid; ch < 1024; ch += 256) {
      int row = ch >> 3, seg = ch & 7;
      *reinterpret_cast<uint4*>(ybf + ybase + (size_t)row * 64 + seg * 8) =
          *reinterpret_cast<const uint4*>(&Cs[row * 72 + seg * 8]);
    }
  }
}

// ---------------------------------------------------------------------------
// K7: h = relu(Wg . [x2 | y0 | y1] + bg) (verified round 8)
__global__ __launch_bounds__(256) void k_wg(
    const unsigned short* __restrict__ x2bf,
    const unsigned short* __restrict__ ybf,
    const unsigned short* __restrict__ wgbf,
    const float* __restrict__ bg,
    unsigned short* __restrict__ hout, int NT)
{
  __shared__ __align__(16) unsigned short As[128 * 72];
  __shared__ __align__(16) unsigned short Ws[64 * 200];
  const int pt = blockIdx.x & 7;
  const int btl = blockIdx.x >> 3;
  const int tid = threadIdx.x, lane = tid & 63, wid = tid >> 6;
  const int wr = wid >> 1, wc = wid & 1;

  for (int ch = tid; ch < 1536; ch += 256) {
    int row = ch / 24, seg = ch % 24;
    *reinterpret_cast<uint4*>(&Ws[row * 200 + seg * 8]) =
        *reinterpret_cast<const uint4*>(wgbf + row * 192 + seg * 8);
  }

  f32x4 acc[4][2];
#pragma unroll
  for (int mi = 0; mi < 4; ++mi)
#pragma unroll
    for (int ni = 0; ni < 2; ++ni) acc[mi][ni] = f32x4{0.f, 0.f, 0.f, 0.f};

  for (int ks = 0; ks < 3; ++ks) {
    const unsigned short* src = (ks == 0)
        ? x2bf + ((size_t)btl * 1024 + pt * 128) * 64
        : ybf + (((size_t)((ks - 1) * NT + btl)) * 1024 + pt * 128) * 64;
    __syncthreads();
    for (int ch = tid; ch < 1024; ch += 256) {
      int row = ch >> 3, seg = ch & 7;
      *reinterpret_cast<uint4*>(&As[row * 72 + seg * 8]) =
          *reinterpret_cast<const uint4*>(src + (size_t)row * 64 + seg * 8);
    }
    __syncthreads();
#pragma unroll
    for (int kk = 0; kk < 2; ++kk) {
      bf16x8 a[4], bfr[2];
#pragma unroll
      for (int mi = 0; mi < 4; ++mi)
        a[mi] = *reinterpret_cast<const bf16x8*>(
            &As[(wr * 64 + mi * 16 + (lane & 15)) * 72 + kk * 32 + (lane >> 4) * 8]);
#pragma unroll
      for (int ni = 0; ni < 2; ++ni)
        bfr[ni] = *reinterpret_cast<const bf16x8*>(
            &Ws[(wc * 32 + ni * 16 + (lane & 15)) * 200 + ks * 64 + kk * 32 + (lane >> 4) * 8]);
#pragma unroll
      for (int mi = 0; mi < 4; ++mi)
#pragma unroll
        for (int ni = 0; ni < 2; ++ni)
          acc[mi][ni] = __builtin_amdgcn_mfma_f32_16x16x32_bf16(a[mi], bfr[ni], acc[mi][ni], 0, 0, 0);
    }
  }

  __syncthreads();
#pragma unroll
  for (int mi = 0; mi < 4; ++mi)
#pragma unroll
    for (int ni = 0; ni < 2; ++ni)
#pragma unroll
      for (int rr = 0; rr < 4; ++rr) {
        int row = wr * 64 + mi * 16 + (lane >> 4) * 4 + rr;
        int col = wc * 32 + ni * 16 + (lane & 15);
        As[row * 72 + col] = f2bf(fmaxf(acc[mi][ni][rr] + bg[col], 0.f));
      }
  __syncthreads();
  const size_t hbase = ((size_t)btl * 1024 + pt * 128) * 64;
  for (int ch = tid; ch < 1024; ch += 256) {
    int row = ch >> 3, seg = ch & 7;
    *reinterpret_cast<uint4*>(hout + hbase + (size_t)row * 64 + seg * 8) =
        *reinterpret_cast<const uint4*>(&As[row * 72 + seg * 8]);
  }
}

// ---------------------------------------------------------------------------
// K8: micro-fusion via MFMA (verified round 7)
__global__ __launch_bounds__(256) void k_fuse2(
    const unsigned short* __restrict__ h0, const unsigned short* __restrict__ h1,
    const unsigned short* __restrict__ wadpB, const unsigned short* __restrict__ w0fB,
    const float* __restrict__ badp, float* __restrict__ otmp)
{
  __shared__ __align__(16) unsigned short As[128 * 136];
  __shared__ __align__(16) unsigned short Bs[64 * 136];
  __shared__ __align__(16) unsigned short Cs[64 * 72];
  const int ntile = blockIdx.x, btl = blockIdx.y;
  const int n0 = ntile * 128;
  const int tid = threadIdx.x, lane = tid & 63, wid = tid >> 6;

  for (int ch = tid; ch < 2048; ch += 256) {
    int half = ch >> 10, r = (ch >> 3) & 127, seg = ch & 7;
    const unsigned short* src = half ? h1 : h0;
    *reinterpret_cast<uint4*>(&As[r * 136 + half * 64 + seg * 8]) =
        *reinterpret_cast<const uint4*>(src + ((size_t)btl * 1024 + n0 + r) * 64 + seg * 8);
  }
  for (int ch = tid; ch < 1024; ch += 256) {
    int r = ch >> 4, seg = ch & 15;
    *reinterpret_cast<uint4*>(&Bs[r * 136 + seg * 8]) =
        *reinterpret_cast<const uint4*>(wadpB + r * 128 + seg * 8);
  }
  for (int ch = tid; ch < 512; ch += 256) {
    int r = ch >> 3, seg = ch & 7;
    *reinterpret_cast<uint4*>(&Cs[r * 72 + seg * 8]) =
        *reinterpret_cast<const uint4*>(w0fB + r * 64 + seg * 8);
  }
  __syncthreads();

  f32x4 aU[2][4], aF0[2][4], aF1[2][4];
#pragma unroll
  for (int mi = 0; mi < 2; ++mi)
#pragma unroll
    for (int ni = 0; ni < 4; ++ni) {
      aU[mi][ni] = f32x4{0.f, 0.f, 0.f, 0.f};
      aF0[mi][ni] = f32x4{0.f, 0.f, 0.f, 0.f};
      aF1[mi][ni] = f32x4{0.f, 0.f, 0.f, 0.f};
    }

  bf16x8 a[2][4];
#pragma unroll
  for (int mi = 0; mi < 2; ++mi)
#pragma unroll
    for (int kk = 0; kk < 4; ++kk)
      a[mi][kk] = *reinterpret_cast<const bf16x8*>(
          &As[(wid * 32 + mi * 16 + (lane & 15)) * 136 + kk * 32 + (lane >> 4) * 8]);

#pragma unroll
  for (int kk = 0; kk < 4; ++kk)
#pragma unroll
    for (int ni = 0; ni < 4; ++ni) {
      bf16x8 bw = *reinterpret_cast<const bf16x8*>(
          &Bs[(ni * 16 + (lane & 15)) * 136 + kk * 32 + (lane >> 4) * 8]);
#pragma unroll
      for (int mi = 0; mi < 2; ++mi)
        aU[mi][ni] = __builtin_amdgcn_mfma_f32_16x16x32_bf16(a[mi][kk], bw, aU[mi][ni], 0, 0, 0);
    }
#pragma unroll
  for (int kk = 0; kk < 2; ++kk)
#pragma unroll
    for (int ni = 0; ni < 4; ++ni) {
      bf16x8 cw = *reinterpret_cast<const bf16x8*>(
          &Cs[(ni * 16 + (lane & 15)) * 72 + kk * 32 + (lane >> 4) * 8]);
#pragma unroll
      for (int mi = 0; mi < 2; ++mi) {
        aF0[mi][ni] = __builtin_amdgcn_mfma_f32_16x16x32_bf16(a[mi][kk], cw, aF0[mi][ni], 0, 0, 0);
        aF1[mi][ni] = __builtin_amdgcn_mfma_f32_16x16x32_bf16(a[mi][kk + 2], cw, aF1[mi][ni], 0, 0, 0);
      }
    }

  float bcol[4];
#pragma unroll
  for (int ni = 0; ni < 4; ++ni) bcol[ni] = badp[ni * 16 + (lane & 15)];

#pragma unroll
  for (int mi = 0; mi < 2; ++mi)
#pragma unroll
    for (int rr = 0; rr < 4; ++rr) {
      float s0 = 0.f, s1 = 0.f;
#pragma unroll
      for (int ni = 0; ni < 4; ++ni) {
        float u = aU[mi][ni][rr] + bcol[ni];
        s0 += aF0[mi][ni][rr] * u;
        s1 += aF1[mi][ni][rr] * u;
      }
#pragma unroll
      for (int off = 1; off < 16; off <<= 1) {
        s0 += __shfl_xor(s0, off);
        s1 += __shfl_xor(s1, off);
      }
      float mmax = fmaxf(s0, s1);
      float e0 = __expf(s0 - mmax), e1 = __expf(s1 - mmax);
      float a0w = e0 / (e0 + e1);
      int row = wid * 32 + mi * 16 + (lane >> 4) * 4 + rr;
      size_t base = ((size_t)btl * 1024 + n0 + row) * 64;
#pragma unroll
      for (int ni = 0; ni < 4; ++ni)
        otmp[base + ni * 16 + (lane & 15)] =
            a0w * aF0[mi][ni][rr] + (1.f - a0w) * aF1[mi][ni][rr];
    }
}

// ---------------------------------------------------------------------------
// K9: otmp -> out [b][c][n][t] (verified round 7)
__global__ __launch_bounds__(256) void k_otr(
    const float* __restrict__ otmp, float* __restrict__ out, int b0)
{
  __shared__ __align__(16) float tile[160 * 68];
  const int nb = blockIdx.x;
  const int bl = blockIdx.y;
  const int b = b0 + bl;
  const int tid = threadIdx.x;

  for (int ch = tid; ch < 2560; ch += 256) {
    int t = ch >> 7, rem = ch & 127, nl = rem >> 4, seg = rem & 15;
    *reinterpret_cast<float4*>(&tile[(nl * 20 + t) * 68 + seg * 4]) =
        *reinterpret_cast<const float4*>(
            otmp + ((size_t)(bl * 20 + t) * 1024 + nb * 8 + nl) * 64 + seg * 4);
  }
  __syncthreads();
  for (int ch = tid; ch < 2560; ch += 256) {
    int tq = ch % 5, pair = ch / 5;
    int nl = pair & 7, cc = pair >> 3;
    float4 v;
    v.x = tile[(nl * 20 + tq * 4 + 0) * 68 + cc];
    v.y = tile[(nl * 20 + tq * 4 + 1) * 68 + cc];
    v.z = tile[(nl * 20 + tq * 4 + 2) * 68 + cc];
    v.w = tile[(nl * 20 + tq * 4 + 3) * 68 + cc];
    *reinterpret_cast<float4*>(
        out + ((size_t)(b * 64 + cc) * 1024 + nb * 8 + nl) * 20 + tq * 4) = v;
  }
}

// ---------------------------------------------------------------------------
extern "C" void kernel_launch(void* const* d_in, const int* in_sizes, int n_in,
                              void* d_out, int out_size, void* d_ws, size_t ws_size,
                              hipStream_t stream) {
  (void)in_sizes; (void)n_in; (void)out_size;
  const float* x    = (const float*)d_in[0];
  const float* tem  = (const float*)d_in[1];
  const float* A0   = (const float*)d_in[2];
  const float* A1   = (const float*)d_in[3];
  const float* A2   = (const float*)d_in[4];
  const float* A3   = (const float*)d_in[5];
  const float* wtc  = (const float*)d_in[6];
  const float* btc  = (const float*)d_in[7];
  const float* wq   = (const float*)d_in[8];
  const float* bq   = (const float*)d_in[9];
  const float* wk   = (const float*)d_in[10];
  const float* bk   = (const float*)d_in[11];
  const float* wv   = (const float*)d_in[12];
  const float* bv   = (const float*)d_in[13];
  const float* wo   = (const float*)d_in[14];
  const float* bo   = (const float*)d_in[15];
  const float* wg0  = (const float*)d_in[16];
  const float* bg0  = (const float*)d_in[17];
  const float* wg1  = (const float*)d_in[18];
  const float* bg1  = (const float*)d_in[19];
  const float* wadp = (const float*)d_in[20];
  const float* badp = (const float*)d_in[21];
  const float* w0f  = (const float*)d_in[22];

  char* ws = (char*)d_ws;
  unsigned short* wadpB = (unsigned short*)(ws + WADPB_OFF);
  unsigned short* w0fB  = (unsigned short*)(ws + W0FB_OFF);
  unsigned short* wg0bf = (unsigned short*)(ws + WG0_OFF);
  unsigned short* wg1bf = (unsigned short*)(ws + WG1_OFF);
  unsigned short* wtcB  = (unsigned short*)(ws + WTCB_OFF);
  unsigned short* wqkvB = (unsigned short*)(ws + WQKVB_OFF);
  unsigned short* woB   = (unsigned short*)(ws + WOB_OFF);
  unsigned short* Abf   = (unsigned short*)(ws + ABF_OFF);

  // per-b slab sizes (bytes)
  const size_t SBH  = (size_t)20480 * 64 * 2;    // 2.62 MB  (xc / attout / x2 / h0)
  const size_t SBT  = (size_t)20480 * 32 * 2;    // 1.31 MB  (temT)
  const size_t SBQ  = (size_t)20480 * 192 * 2;   // 7.86 MB  (qkv; x2+x2T overlay)
  const size_t SBY  = 2 * SBH;                   // 5.24 MB  (y pair / otmp fp32)
  int CB = 1;
  {
    const int cands[4] = {16, 8, 4, 2};
    for (int i = 0; i < 4; ++i) {
      size_t need = CHUNK0 + (size_t)cands[i] * (SBH + SBT + SBQ + SBY + SBH);
      if (need <= ws_size) { CB = cands[i]; break; }
    }
  }
  const int NT = CB * TO;
  const size_t XC0  = CHUNK0;
  const size_t TT0  = XC0 + (size_t)CB * SBH;
  const size_t QKV0 = TT0 + (size_t)CB * SBT;
  const size_t Y0   = QKV0 + (size_t)CB * SBQ;
  const size_t H00  = Y0 + (size_t)CB * SBY;
  unsigned short* xc     = (unsigned short*)(ws + XC0);
  unsigned short* temT   = (unsigned short*)(ws + TT0);
  unsigned short* qkvbuf = (unsigned short*)(ws + QKV0);
  unsigned short* attout = (unsigned short*)(ws + XC0);            // overlay xc (dead)
  unsigned short* x2bf   = (unsigned short*)(ws + QKV0);           // overlay qkv (dead)
  unsigned short* x2t    = (unsigned short*)(ws + QKV0 + (size_t)CB * SBH);
  unsigned short* ybuf   = (unsigned short*)(ws + Y0);
  unsigned short* h0     = (unsigned short*)(ws + H00);
  unsigned short* h1     = x2t;                                    // overlay x2t (dead)
  float* otmp            = (float*)(ws + Y0);                      // overlay ybuf (dead)
  float* out = (float*)d_out;

  k_prep_w<<<dim3(256), dim3(256), 0, stream>>>(wtc, wq, wk, wv, wo, wadp, w0f,
                                                wg0, wg1, wadpB, w0fB, wg0bf, wg1bf,
                                                wtcB, wqkvB, woB);
  k_prep_a<<<dim3(4096), dim3(256), 0, stream>>>(A0, A1, A2, A3, Abf);

  for (int b0 = 0; b0 < BB; b0 += CB) {
    k_ttr<<<dim3(64, CB), dim3(256), 0, stream>>>(tem, temT, b0);
    k_conv<<<dim3(160, CB), dim3(256), 0, stream>>>(x, wtcB, btc, xc, b0);
    k_qkv<<<dim3(160, CB), dim3(256), 0, stream>>>(xc, temT, wqkvB, bq, bk, bv, qkvbuf);
    k_att<<<dim3(CB * 128), dim3(256), 0, stream>>>(qkvbuf, attout);
    k_wo<<<dim3(160, CB), dim3(256), 0, stream>>>(attout, woB, bo, x2bf);
    k_trx2<<<dim3(16, NT), dim3(256), 0, stream>>>(x2bf, x2t);
    k_nconv<<<dim3((NT / 2) * 8, 2), dim3(256), 0, stream>>>(Abf, x2t, ybuf, NT);
    k_wg<<<dim3(8 * NT), dim3(256), 0, stream>>>(x2bf, ybuf, wg0bf, bg0, h0, NT);
    k_nconv<<<dim3((NT / 2) * 8, 2), dim3(256), 0, stream>>>(Abf + 2 * 1024 * 1024, x2t, ybuf, NT);
    k_wg<<<dim3(8 * NT), dim3(256), 0, stream>>>(x2bf, ybuf, wg1bf, bg1, h1, NT);
    k_fuse2<<<dim3(8, NT), dim3(256), 0, stream>>>(h0, h1, wadpB, w0fB, badp, otmp);
    k_otr<<<dim3(128, CB), dim3(256), 0, stream>>>(otmp, out, b0);
  }
}